// Round 1
// baseline (465.076 us; speedup 1.0000x reference)
//
#include <hip/hip_runtime.h>
#include <hip/hip_bf16.h>

#define N_NODES 10000
#define IN_DIM 256
#define HID 512      // HEADS*HIDDEN
#define HEADS 8
#define OUT_DIM 256
#define NEG 0.2f
#define CAP 512      // max cached degree per node (actual max ~70)

typedef __hip_bfloat16 bf16;

// mode==1 -> data is fp32; mode==0 -> data is bf16
__device__ __forceinline__ float ldm(const void* p, long i, int mode){
  if(mode) return ((const float*)p)[i];
  return __bfloat162float(((const bf16*)p)[i]);
}

// Sniff whether float tensors are stored as bf16 or f32.
// If f32: even u16 indices are fp32 low-mantissa bits -> random exponents.
__global__ void detect_k(const unsigned short* w1raw, int* mode){
  if(threadIdx.x==0 && blockIdx.x==0){
    int bad=0;
    for(int i=0;i<512;i++){
      unsigned int u = ((unsigned int)w1raw[i])<<16;
      float f = __uint_as_float(u);
      if(!(f==f) || fabsf(f) > 100.0f) bad++;
    }
    *mode = (bad>10) ? 1 : 0;
  }
}

__global__ void hist_k(const int* dst, int* cnt, int E){
  int e = blockIdx.x*256 + threadIdx.x;
  if(e<E) atomicAdd(&cnt[dst[e]], 1);
}

// single-block exclusive scan of n counts -> offsets[0..n], cursor copy.
// counts may alias cursor (read-before-write per index).
__global__ void scan_k(const int* counts, int* offsets, int* cursor, int n){
  __shared__ int tmp[1024];
  int t = threadIdx.x;
  int base = 0;
  for(int start=0; start<n; start+=1024){
    int i = start+t;
    int v = (i<n)? counts[i] : 0;
    tmp[t]=v;
    __syncthreads();
    for(int off=1; off<1024; off<<=1){
      int u = (t>=off)? tmp[t-off] : 0;
      __syncthreads();
      tmp[t] += u;
      __syncthreads();
    }
    if(i<n){ int excl = base + tmp[t] - v; offsets[i]=excl; cursor[i]=excl; }
    base += tmp[1023];
    __syncthreads();
  }
  if(t==0) offsets[n]=base;
}

__global__ void scatter_k(const int* src, const int* dst, int* cursor, int* ssort, int E){
  int e = blockIdx.x*256 + threadIdx.x;
  if(e<E){
    int d = dst[e];
    int pos = atomicAdd(&cursor[d], 1);
    ssort[pos] = src[e];
  }
}

// C[M,N] f32 = A[M,K] @ B[K,N]; A dtype: a_f32 ? f32 : mode; B dtype: mode.
// block 256 threads, 64x64 tile, 4x4 per thread, BK=16.
__global__ void gemm_tiled(const void* A, const void* B, float* C,
                           int M, int N, int K, int a_f32, const int* modep){
  int md = *modep;
  int am = a_f32 ? 1 : md;
  int bm = md;
  __shared__ float As[16][65];
  __shared__ float Bs[16][65];
  int t = threadIdx.x;
  int tx = t & 15, ty = t >> 4;
  int mbase = blockIdx.y * 64;
  int nbase = blockIdx.x * 64;
  float acc[4][4];
  #pragma unroll
  for(int i=0;i<4;i++)
    #pragma unroll
    for(int j=0;j<4;j++) acc[i][j]=0.f;
  for(int k0=0;k0<K;k0+=16){
    #pragma unroll
    for(int l=0;l<4;l++){
      int e = t + l*256;
      int m = e >> 4, kk = e & 15;
      int gr = mbase + m;
      As[kk][m] = (gr < M) ? ldm(A, (long)gr*K + k0 + kk, am) : 0.f;
    }
    #pragma unroll
    for(int l=0;l<4;l++){
      int e = t + l*256;
      int kk = e >> 6, nn = e & 63;
      Bs[kk][nn] = ldm(B, (long)(k0+kk)*N + nbase + nn, bm);
    }
    __syncthreads();
    #pragma unroll
    for(int kk=0;kk<16;kk++){
      float a[4], b[4];
      #pragma unroll
      for(int i=0;i<4;i++){ a[i]=As[kk][ty*4+i]; b[i]=Bs[kk][tx*4+i]; }
      #pragma unroll
      for(int i=0;i<4;i++)
        #pragma unroll
        for(int j=0;j<4;j++) acc[i][j] += a[i]*b[j];
    }
    __syncthreads();
  }
  #pragma unroll
  for(int i=0;i<4;i++){
    int gr = mbase + ty*4 + i;
    if(gr < M){
      #pragma unroll
      for(int j=0;j<4;j++) C[(long)gr*N + nbase + tx*4 + j] = acc[i][j];
    }
  }
}

// el/er for layer 1: block 512 = 8 waves, wave w handles head w, lane d.
__global__ void dots1_k(const float* feat1, const void* al, const void* ar,
                        float* el, float* er, const int* modep){
  int md = *modep;
  int n = blockIdx.x;
  int hd = threadIdx.x;          // 0..511 = h*64+d
  int h = hd >> 6, d = hd & 63;
  float v = feat1[(long)n*HID + hd];
  float l = v * ldm(al, hd, md);
  float r = v * ldm(ar, hd, md);
  #pragma unroll
  for(int off=32; off>0; off>>=1){ l += __shfl_down(l,off); r += __shfl_down(r,off); }
  if(d==0){ el[n*HEADS+h]=l; er[n*HEADS+h]=r; }
}

// el/er for layer 2 (H=1, D=256): block 256 per node.
__global__ void dots2_k(const float* feat2, const void* al, const void* ar,
                        float* el, float* er, const int* modep){
  int md = *modep;
  int n = blockIdx.x, t = threadIdx.x;
  float v = feat2[(long)n*OUT_DIM + t];
  float l = v * ldm(al, t, md);
  float r = v * ldm(ar, t, md);
  #pragma unroll
  for(int off=32; off>0; off>>=1){ l += __shfl_down(l,off); r += __shfl_down(r,off); }
  __shared__ float sl[4], sr[4];
  int wv = t>>6;
  if((t&63)==0){ sl[wv]=l; sr[wv]=r; }
  __syncthreads();
  if(t==0){ el[n]=sl[0]+sl[1]+sl[2]+sl[3]; er[n]=sr[0]+sr[1]+sr[2]+sr[3]; }
}

// Layer-1 edge softmax + aggregate + ELU. One block per dst node.
__global__ void agg1_k(const float* feat1, const float* el, const float* er,
                       const int* offs, const int* srcs, float* x){
  int n = blockIdx.x, t = threadIdx.x;    // 256 threads
  int off = offs[n];
  int deg = offs[n+1]-off;
  __shared__ float wsum[8], ers[8];
  __shared__ float wlds[CAP*8];
  if(t<8){ wsum[t]=0.f; ers[t]=er[n*HEADS+t]; }
  __syncthreads();
  bool fits = (deg<=CAP);
  int tot = deg*HEADS;
  for(int p=t; p<tot; p+=256){
    int i = p>>3, h2 = p&7;
    int s = srcs[off+i];
    float e = el[s*HEADS+h2] + ers[h2];
    e = e>0.f ? e : NEG*e;
    float w = __expf(e);
    if(fits) wlds[p]=w;
    atomicAdd(&wsum[h2], w);
  }
  __syncthreads();
  if(t<8) wsum[t] = 1.f/wsum[t];
  __syncthreads();
  int j0=t, j1=t+256;
  int h0=j0>>6, h1=j1>>6;
  float er0=ers[h0], er1v=ers[h1];
  float inv0=wsum[h0], inv1=wsum[h1];
  float acc0=0.f, acc1=0.f;
  for(int i=0;i<deg;i++){
    int s = srcs[off+i];
    float w0, w1;
    if(fits){ w0=wlds[i*8+h0]; w1=wlds[i*8+h1]; }
    else{
      float e0 = el[s*HEADS+h0]+er0; e0=e0>0.f?e0:NEG*e0; w0=__expf(e0);
      float e1 = el[s*HEADS+h1]+er1v; e1=e1>0.f?e1:NEG*e1; w1=__expf(e1);
    }
    const float* fr = feat1 + (long)s*HID;
    acc0 += w0*inv0 * fr[j0];
    acc1 += w1*inv1 * fr[j1];
  }
  acc0 = acc0>0.f ? acc0 : __expf(acc0)-1.f;   // ELU
  acc1 = acc1>0.f ? acc1 : __expf(acc1)-1.f;
  x[(long)n*HID + j0] = acc0;
  x[(long)n*HID + j1] = acc1;
}

// Layer-2 edge softmax + aggregate -> final output. One block per dst node.
__global__ void agg2_k(const float* feat2, const float* el, const float* er,
                       const int* offs, const int* srcs, void* out, const int* modep){
  int md = *modep;
  int n = blockIdx.x, t = threadIdx.x;    // 256 threads
  int off = offs[n];
  int deg = offs[n+1]-off;
  __shared__ float wsum1;
  __shared__ float wlds[CAP];
  if(t==0) wsum1=0.f;
  __syncthreads();
  float ern = er[n];
  bool fits = (deg<=CAP);
  float part = 0.f;
  for(int i=t; i<deg; i+=256){
    int s = srcs[off+i];
    float e = el[s]+ern; e = e>0.f ? e : NEG*e;
    float w = __expf(e);
    if(fits) wlds[i]=w;
    part += w;
  }
  #pragma unroll
  for(int o=32;o>0;o>>=1) part += __shfl_down(part,o);
  if((t&63)==0) atomicAdd(&wsum1, part);
  __syncthreads();
  float inv = 1.f/wsum1;
  float acc = 0.f;
  for(int i=0;i<deg;i++){
    int s = srcs[off+i];
    float w;
    if(fits) w = wlds[i];
    else { float e=el[s]+ern; e=e>0.f?e:NEG*e; w=__expf(e); }
    acc += w*inv * feat2[(long)s*OUT_DIM + t];
  }
  long oi = (long)n*OUT_DIM + t;
  if(md) ((float*)out)[oi] = acc;
  else   ((bf16*)out)[oi] = __float2bfloat16(acc);
}

extern "C" void kernel_launch(void* const* d_in, const int* in_sizes, int n_in,
                              void* d_out, int out_size, void* d_ws, size_t ws_size,
                              hipStream_t stream){
  (void)n_in; (void)out_size; (void)ws_size;
  const void* h_in = d_in[0];
  const void* W1   = d_in[1];
  const void* al1  = d_in[2];
  const void* ar1  = d_in[3];
  const void* W2   = d_in[4];
  const void* al2  = d_in[5];
  const void* ar2  = d_in[6];
  const int* src = (const int*)d_in[7];
  const int* dst = (const int*)d_in[8];
  int E = in_sizes[7];

  char* ws = (char*)d_ws;
  size_t o = 0;
  auto alloc = [&](size_t b){ size_t c=o; o += (b+255)&~(size_t)255; return c; };
  float* feat1 = (float*)(ws + alloc((size_t)N_NODES*HID*4));
  float* xbuf  = (float*)(ws + alloc((size_t)N_NODES*HID*4));
  float* el1   = (float*)(ws + alloc((size_t)N_NODES*HEADS*4));
  float* er1   = (float*)(ws + alloc((size_t)N_NODES*HEADS*4));
  int* offs    = (int*)(ws + alloc((size_t)(N_NODES+1)*4));
  int* cursor  = (int*)(ws + alloc((size_t)N_NODES*4));
  int* ssort   = (int*)(ws + alloc((size_t)E*4));
  int* modep   = (int*)(ws + alloc(256));
  // dead-buffer aliasing: feat2 over feat1's space is NOT safe (feat1 read in agg1
  // while feat2 written after agg1 -> OK actually, but keep separate for clarity-free
  // correctness this round; reuse el1/er1 for el2/er2 (el1 dead after agg1).
  float* feat2 = (float*)(ws + alloc((size_t)N_NODES*OUT_DIM*4));
  float* el2 = el1;
  float* er2 = er1;

  hipMemsetAsync(cursor, 0, N_NODES*4, stream);
  detect_k<<<1,64,0,stream>>>((const unsigned short*)W1, modep);
  hist_k<<<(E+255)/256,256,0,stream>>>(dst, cursor, E);
  scan_k<<<1,1024,0,stream>>>(cursor, offs, cursor, N_NODES);
  scatter_k<<<(E+255)/256,256,0,stream>>>(src, dst, cursor, ssort, E);

  gemm_tiled<<<dim3(HID/64,(N_NODES+63)/64),256,0,stream>>>(
      h_in, W1, feat1, N_NODES, HID, IN_DIM, 0, modep);
  dots1_k<<<N_NODES,512,0,stream>>>(feat1, al1, ar1, el1, er1, modep);
  agg1_k<<<N_NODES,256,0,stream>>>(feat1, el1, er1, offs, ssort, xbuf);

  gemm_tiled<<<dim3(OUT_DIM/64,(N_NODES+63)/64),256,0,stream>>>(
      xbuf, W2, feat2, N_NODES, OUT_DIM, HID, 1, modep);
  dots2_k<<<N_NODES,256,0,stream>>>(feat2, al2, ar2, el2, er2, modep);
  agg2_k<<<N_NODES,256,0,stream>>>(feat2, el2, er2, offs, ssort, d_out, modep);
}

// Round 2
// 313.953 us; speedup vs baseline: 1.4814x; 1.4814x over previous
//
#include <hip/hip_runtime.h>
#include <hip/hip_bf16.h>

#define N_NODES 10000
#define IN_DIM 256
#define HID 512      // HEADS*HIDDEN
#define HEADS 8
#define OUT_DIM 256
#define NEG 0.2f
#define CAP 512      // max cached degree per node (actual max ~70)

typedef __hip_bfloat16 bf16;
typedef __attribute__((ext_vector_type(8))) short short8;
typedef __attribute__((ext_vector_type(4))) float f32x4;

// mode==1 -> data is fp32; mode==0 -> data is bf16
__device__ __forceinline__ float ldm(const void* p, long i, int mode){
  if(mode) return ((const float*)p)[i];
  return __bfloat162float(((const bf16*)p)[i]);
}
__device__ __forceinline__ unsigned short f2bf(float f){
  bf16 b = __float2bfloat16(f);
  return *(unsigned short*)&b;
}

// Sniff whether float tensors are stored as bf16 or f32 (parallel).
__global__ void detect_k(const unsigned short* w1raw, int* mode){
  __shared__ int sbad;
  int t = threadIdx.x;
  if(t==0) sbad=0;
  __syncthreads();
  int bad=0;
  for(int i=t;i<512;i+=256){
    unsigned int u = ((unsigned int)w1raw[i])<<16;
    float f = __uint_as_float(u);
    if(!(f==f) || fabsf(f) > 100.0f) bad++;
  }
  #pragma unroll
  for(int o=32;o>0;o>>=1) bad += __shfl_down(bad,o);
  if((t&63)==0) atomicAdd(&sbad, bad);
  __syncthreads();
  if(t==0) *mode = (sbad>10) ? 1 : 0;
}

__global__ void hist_k(const int* dst, int* cnt, int E){
  int e = blockIdx.x*256 + threadIdx.x;
  if(e<E) atomicAdd(&cnt[dst[e]], 1);
}

// single-block scan: 1024 threads x 10-node serial chunks, one 1024-wide scan.
// counts may alias cursor (each index read+written by the same thread, reads
// happen before the barrier, writes after).
__global__ void scan_k(const int* counts, int* offsets, int* cursor, int n){
  __shared__ int tmp[1024];
  const int CH = 10;   // 1024*10 >= 10000
  int t = threadIdx.x;
  int base = t*CH;
  int loc[CH];
  int s = 0;
  #pragma unroll
  for(int i=0;i<CH;i++){
    int idx = base+i;
    int v = (idx<n) ? counts[idx] : 0;
    loc[i] = s; s += v;
  }
  tmp[t] = s;
  __syncthreads();
  for(int off=1; off<1024; off<<=1){
    int u = (t>=off) ? tmp[t-off] : 0;
    __syncthreads();
    tmp[t] += u;
    __syncthreads();
  }
  int excl = tmp[t] - s;
  #pragma unroll
  for(int i=0;i<CH;i++){
    int idx = base+i;
    if(idx<n){ int o = excl + loc[i]; offsets[idx]=o; cursor[idx]=o; }
  }
  if(t==1023) offsets[n] = tmp[1023];
}

__global__ void scatter_k(const int* src, const int* dst, int* cursor, int* ssort, int E){
  int e = blockIdx.x*256 + threadIdx.x;
  if(e<E){
    int d = dst[e];
    int pos = atomicAdd(&cursor[d], 1);
    ssort[pos] = src[e];
  }
}

// Repack (possibly f32) input to bf16 flat.
__global__ void repack_k(const void* in, unsigned short* out, long n, const int* modep){
  int md = *modep;
  long i = (long)blockIdx.x*256 + threadIdx.x;
  if(i<n){
    if(md) out[i] = f2bf(((const float*)in)[i]);
    else   out[i] = ((const unsigned short*)in)[i];
  }
}

// Repack + transpose: in [K][N] -> out [N][K] bf16.
__global__ void repack_t_k(const void* in, unsigned short* out, int K, int N, const int* modep){
  int md = *modep;
  long i = (long)blockIdx.x*256 + threadIdx.x;
  long tot = (long)K*N;
  if(i<tot){
    int k = (int)(i / N), n = (int)(i % N);
    unsigned short v = md ? f2bf(((const float*)in)[i]) : ((const unsigned short*)in)[i];
    out[(long)n*K + k] = v;
  }
}

// C[M,N] f32 = A[M,K]bf16 @ Bt[N,K]bf16^T. 128x128 tile, BK=32, 4 waves,
// each wave 64x64 via 4x4 mfma_f32_16x16x32_bf16 frags.
// LDS rows padded to 40 shorts (80B, bank stride 20 -> worst 2-way, free).
__global__ __launch_bounds__(256) void gemm_mfma(const unsigned short* A, const unsigned short* Bt,
                                                 float* C, int M, int N, int K){
  __shared__ short As[128*40];
  __shared__ short Bs[128*40];
  int t = threadIdx.x;
  int lane = t & 63, wave = t >> 6;
  int l15 = lane & 15, quad = lane >> 4;
  int wm = (wave>>1)*64, wn = (wave&1)*64;
  int mbase = blockIdx.y*128, nbase = blockIdx.x*128;

  f32x4 acc[4][4];
  #pragma unroll
  for(int i=0;i<4;i++)
    #pragma unroll
    for(int j=0;j<4;j++) acc[i][j] = (f32x4){0.f,0.f,0.f,0.f};

  // staging: 256 threads x 2 chunks of 8 bf16 cover 128 rows x 32 k
  int c0 = t, c1 = t + 256;
  int row0 = c0>>2, kk0 = (c0&3)*8;
  int row1 = c1>>2, kk1 = (c1&3)*8;
  long arow0 = (long)(mbase+row0)*K, arow1 = (long)(mbase+row1)*K;
  long brow0 = (long)(nbase+row0)*K, brow1 = (long)(nbase+row1)*K;
  bool av0 = (mbase+row0) < M, av1 = (mbase+row1) < M;

  for(int k0=0;k0<K;k0+=32){
    short8 a0 = (short8){0,0,0,0,0,0,0,0}, a1 = a0;
    if(av0) a0 = *(const short8*)(A + arow0 + k0 + kk0);
    if(av1) a1 = *(const short8*)(A + arow1 + k0 + kk1);
    short8 b0 = *(const short8*)(Bt + brow0 + k0 + kk0);
    short8 b1 = *(const short8*)(Bt + brow1 + k0 + kk1);
    __syncthreads();   // previous iter's ds_reads done before overwrite
    *(short8*)(As + row0*40 + kk0) = a0;
    *(short8*)(As + row1*40 + kk1) = a1;
    *(short8*)(Bs + row0*40 + kk0) = b0;
    *(short8*)(Bs + row1*40 + kk1) = b1;
    __syncthreads();
    short8 af[4], bfr[4];
    #pragma unroll
    for(int mi=0;mi<4;mi++) af[mi]  = *(short8*)(As + (wm + mi*16 + l15)*40 + quad*8);
    #pragma unroll
    for(int ni=0;ni<4;ni++) bfr[ni] = *(short8*)(Bs + (wn + ni*16 + l15)*40 + quad*8);
    #pragma unroll
    for(int mi=0;mi<4;mi++)
      #pragma unroll
      for(int ni=0;ni<4;ni++)
        acc[mi][ni] = __builtin_amdgcn_mfma_f32_16x16x32_bf16(af[mi], bfr[ni], acc[mi][ni], 0,0,0);
  }

  #pragma unroll
  for(int mi=0;mi<4;mi++){
    #pragma unroll
    for(int ni=0;ni<4;ni++){
      int grow0 = mbase + wm + mi*16 + quad*4;
      int gcol  = nbase + wn + ni*16 + l15;
      #pragma unroll
      for(int r=0;r<4;r++){
        int grow = grow0 + r;
        if(grow < M) C[(long)grow*N + gcol] = acc[mi][ni][r];
      }
    }
  }
}

// el/er for layer 1: block 512 = 8 waves, wave w handles head w, lane d.
__global__ void dots1_k(const float* feat1, const void* al, const void* ar,
                        float* el, float* er, const int* modep){
  int md = *modep;
  int n = blockIdx.x;
  int hd = threadIdx.x;          // 0..511 = h*64+d
  int h = hd >> 6, d = hd & 63;
  float v = feat1[(long)n*HID + hd];
  float l = v * ldm(al, hd, md);
  float r = v * ldm(ar, hd, md);
  #pragma unroll
  for(int off=32; off>0; off>>=1){ l += __shfl_down(l,off); r += __shfl_down(r,off); }
  if(d==0){ el[n*HEADS+h]=l; er[n*HEADS+h]=r; }
}

// el/er for layer 2 (H=1, D=256): block 256 per node.
__global__ void dots2_k(const float* feat2, const void* al, const void* ar,
                        float* el, float* er, const int* modep){
  int md = *modep;
  int n = blockIdx.x, t = threadIdx.x;
  float v = feat2[(long)n*OUT_DIM + t];
  float l = v * ldm(al, t, md);
  float r = v * ldm(ar, t, md);
  #pragma unroll
  for(int off=32; off>0; off>>=1){ l += __shfl_down(l,off); r += __shfl_down(r,off); }
  __shared__ float sl[4], sr[4];
  int wv = t>>6;
  if((t&63)==0){ sl[wv]=l; sr[wv]=r; }
  __syncthreads();
  if(t==0){ el[n]=sl[0]+sl[1]+sl[2]+sl[3]; er[n]=sr[0]+sr[1]+sr[2]+sr[3]; }
}

// Layer-1 edge softmax + aggregate + ELU -> bf16 x. One block per dst node.
__global__ void agg1_k(const float* feat1, const float* el, const float* er,
                       const int* offs, const int* srcs, unsigned short* x){
  int n = blockIdx.x, t = threadIdx.x;    // 256 threads
  int off = offs[n];
  int deg = offs[n+1]-off;
  __shared__ float wsum[8], ers[8];
  __shared__ float wlds[CAP*8];
  if(t<8){ wsum[t]=0.f; ers[t]=er[n*HEADS+t]; }
  __syncthreads();
  bool fits = (deg<=CAP);
  int tot = deg*HEADS;
  for(int p=t; p<tot; p+=256){
    int i = p>>3, h2 = p&7;
    int s = srcs[off+i];
    float e = el[s*HEADS+h2] + ers[h2];
    e = e>0.f ? e : NEG*e;
    float w = __expf(e);
    if(fits) wlds[p]=w;
    atomicAdd(&wsum[h2], w);
  }
  __syncthreads();
  if(t<8) wsum[t] = 1.f/wsum[t];
  __syncthreads();
  int j0=t, j1=t+256;
  int h0=j0>>6, h1=j1>>6;
  float er0=ers[h0], er1v=ers[h1];
  float inv0=wsum[h0], inv1=wsum[h1];
  float acc0=0.f, acc1=0.f;
  for(int i=0;i<deg;i++){
    int s = srcs[off+i];
    float w0, w1;
    if(fits){ w0=wlds[i*8+h0]; w1=wlds[i*8+h1]; }
    else{
      float e0 = el[s*HEADS+h0]+er0; e0=e0>0.f?e0:NEG*e0; w0=__expf(e0);
      float e1 = el[s*HEADS+h1]+er1v; e1=e1>0.f?e1:NEG*e1; w1=__expf(e1);
    }
    const float* fr = feat1 + (long)s*HID;
    acc0 += w0*inv0 * fr[j0];
    acc1 += w1*inv1 * fr[j1];
  }
  acc0 = acc0>0.f ? acc0 : __expf(acc0)-1.f;   // ELU
  acc1 = acc1>0.f ? acc1 : __expf(acc1)-1.f;
  x[(long)n*HID + j0] = f2bf(acc0);
  x[(long)n*HID + j1] = f2bf(acc1);
}

// Layer-2 edge softmax + aggregate -> final output. One block per dst node.
__global__ void agg2_k(const float* feat2, const float* el, const float* er,
                       const int* offs, const int* srcs, void* out, const int* modep){
  int md = *modep;
  int n = blockIdx.x, t = threadIdx.x;    // 256 threads
  int off = offs[n];
  int deg = offs[n+1]-off;
  __shared__ float wsum1;
  __shared__ float wlds[CAP];
  if(t==0) wsum1=0.f;
  __syncthreads();
  float ern = er[n];
  bool fits = (deg<=CAP);
  float part = 0.f;
  for(int i=t; i<deg; i+=256){
    int s = srcs[off+i];
    float e = el[s]+ern; e = e>0.f ? e : NEG*e;
    float w = __expf(e);
    if(fits) wlds[i]=w;
    part += w;
  }
  #pragma unroll
  for(int o=32;o>0;o>>=1) part += __shfl_down(part,o);
  if((t&63)==0) atomicAdd(&wsum1, part);
  __syncthreads();
  float inv = 1.f/wsum1;
  float acc = 0.f;
  for(int i=0;i<deg;i++){
    int s = srcs[off+i];
    float w;
    if(fits) w = wlds[i];
    else { float e=el[s]+ern; e=e>0.f?e:NEG*e; w=__expf(e); }
    acc += w*inv * feat2[(long)s*OUT_DIM + t];
  }
  long oi = (long)n*OUT_DIM + t;
  if(md) ((float*)out)[oi] = acc;
  else   ((bf16*)out)[oi] = __float2bfloat16(acc);
}

extern "C" void kernel_launch(void* const* d_in, const int* in_sizes, int n_in,
                              void* d_out, int out_size, void* d_ws, size_t ws_size,
                              hipStream_t stream){
  (void)n_in; (void)out_size; (void)ws_size;
  const void* h_in = d_in[0];
  const void* W1   = d_in[1];
  const void* al1  = d_in[2];
  const void* ar1  = d_in[3];
  const void* W2   = d_in[4];
  const void* al2  = d_in[5];
  const void* ar2  = d_in[6];
  const int* src = (const int*)d_in[7];
  const int* dst = (const int*)d_in[8];
  int E = in_sizes[7];

  char* ws = (char*)d_ws;
  size_t o = 0;
  auto alloc = [&](size_t b){ size_t c=o; o += (b+255)&~(size_t)255; return c; };
  float* feat1 = (float*)(ws + alloc((size_t)N_NODES*HID*4));
  float* feat2 = (float*)(ws + alloc((size_t)N_NODES*OUT_DIM*4));
  unsigned short* xbuf = (unsigned short*)(ws + alloc((size_t)N_NODES*HID*2));
  unsigned short* abf1 = (unsigned short*)(ws + alloc((size_t)N_NODES*IN_DIM*2));
  unsigned short* wt1  = (unsigned short*)(ws + alloc((size_t)IN_DIM*HID*2));
  unsigned short* wt2  = (unsigned short*)(ws + alloc((size_t)HID*OUT_DIM*2));
  float* el1   = (float*)(ws + alloc((size_t)N_NODES*HEADS*4));
  float* er1   = (float*)(ws + alloc((size_t)N_NODES*HEADS*4));
  int* offs    = (int*)(ws + alloc((size_t)(N_NODES+1)*4));
  int* cursor  = (int*)(ws + alloc((size_t)N_NODES*4));
  int* ssort   = (int*)(ws + alloc((size_t)E*4));
  int* modep   = (int*)(ws + alloc(256));
  float* el2 = el1;   // el1 dead after agg1
  float* er2 = er1;

  hipMemsetAsync(cursor, 0, N_NODES*4, stream);
  detect_k<<<1,256,0,stream>>>((const unsigned short*)W1, modep);
  hist_k<<<(E+255)/256,256,0,stream>>>(dst, cursor, E);
  scan_k<<<1,1024,0,stream>>>(cursor, offs, cursor, N_NODES);
  scatter_k<<<(E+255)/256,256,0,stream>>>(src, dst, cursor, ssort, E);

  // bf16 repacks
  {
    long n1 = (long)N_NODES*IN_DIM;
    repack_k<<<(int)((n1+255)/256),256,0,stream>>>(h_in, abf1, n1, modep);
    long nw1 = (long)IN_DIM*HID;
    repack_t_k<<<(int)((nw1+255)/256),256,0,stream>>>(W1, wt1, IN_DIM, HID, modep);
    long nw2 = (long)HID*OUT_DIM;
    repack_t_k<<<(int)((nw2+255)/256),256,0,stream>>>(W2, wt2, HID, OUT_DIM, modep);
  }

  // layer 1
  gemm_mfma<<<dim3(HID/128,(N_NODES+127)/128),256,0,stream>>>(
      abf1, wt1, feat1, N_NODES, HID, IN_DIM);
  dots1_k<<<N_NODES,512,0,stream>>>(feat1, al1, ar1, el1, er1, modep);
  agg1_k<<<N_NODES,256,0,stream>>>(feat1, el1, er1, offs, ssort, xbuf);

  // layer 2
  gemm_mfma<<<dim3(OUT_DIM/128,(N_NODES+127)/128),256,0,stream>>>(
      xbuf, wt2, feat2, N_NODES, OUT_DIM, HID);
  dots2_k<<<N_NODES,256,0,stream>>>(feat2, al2, ar2, el2, er2, modep);
  agg2_k<<<N_NODES,256,0,stream>>>(feat2, el2, er2, offs, ssort, d_out, modep);
}

// Round 3
// 254.374 us; speedup vs baseline: 1.8283x; 1.2342x over previous
//
#include <hip/hip_runtime.h>
#include <hip/hip_bf16.h>

#define N_NODES 10000
#define IN_DIM 256
#define HID 512      // HEADS*HIDDEN
#define HEADS 8
#define OUT_DIM 256
#define NEG 0.2f
#define CAP 512      // max cached degree per node (actual max ~70)

typedef __hip_bfloat16 bf16;
typedef __attribute__((ext_vector_type(8))) short short8;
typedef __attribute__((ext_vector_type(4))) float f32x4;

// mode==1 -> data is fp32; mode==0 -> data is bf16
__device__ __forceinline__ float ldm(const void* p, long i, int mode){
  if(mode) return ((const float*)p)[i];
  return __bfloat162float(((const bf16*)p)[i]);
}
__device__ __forceinline__ unsigned short f2bf(float f){
  bf16 b = __float2bfloat16(f);
  return *(unsigned short*)&b;
}
__device__ __forceinline__ float bflo(unsigned int u){ return __uint_as_float(u<<16); }
__device__ __forceinline__ float bfhi(unsigned int u){ return __uint_as_float(u&0xffff0000u); }

// Sniff whether float tensors are stored as bf16 or f32 (parallel).
__global__ void detect_k(const unsigned short* w1raw, int* mode){
  __shared__ int sbad;
  int t = threadIdx.x;
  if(t==0) sbad=0;
  __syncthreads();
  int bad=0;
  for(int i=t;i<512;i+=256){
    unsigned int u = ((unsigned int)w1raw[i])<<16;
    float f = __uint_as_float(u);
    if(!(f==f) || fabsf(f) > 100.0f) bad++;
  }
  #pragma unroll
  for(int o=32;o>0;o>>=1) bad += __shfl_down(bad,o);
  if((t&63)==0) atomicAdd(&sbad, bad);
  __syncthreads();
  if(t==0) *mode = (sbad>10) ? 1 : 0;
}

__global__ void hist_k(const int* dst, int* cnt, int E){
  int e = blockIdx.x*256 + threadIdx.x;
  if(e<E) atomicAdd(&cnt[dst[e]], 1);
}

// single-block scan: 1024 threads x 10-node serial chunks, one 1024-wide scan.
__global__ void scan_k(const int* counts, int* offsets, int* cursor, int n){
  __shared__ int tmp[1024];
  const int CH = 10;   // 1024*10 >= 10000
  int t = threadIdx.x;
  int base = t*CH;
  int loc[CH];
  int s = 0;
  #pragma unroll
  for(int i=0;i<CH;i++){
    int idx = base+i;
    int v = (idx<n) ? counts[idx] : 0;
    loc[i] = s; s += v;
  }
  tmp[t] = s;
  __syncthreads();
  for(int off=1; off<1024; off<<=1){
    int u = (t>=off) ? tmp[t-off] : 0;
    __syncthreads();
    tmp[t] += u;
    __syncthreads();
  }
  int excl = tmp[t] - s;
  #pragma unroll
  for(int i=0;i<CH;i++){
    int idx = base+i;
    if(idx<n){ int o = excl + loc[i]; offsets[idx]=o; cursor[idx]=o; }
  }
  if(t==1023) offsets[n] = tmp[1023];
}

__global__ void scatter_k(const int* src, const int* dst, int* cursor, int* ssort, int E){
  int e = blockIdx.x*256 + threadIdx.x;
  if(e<E){
    int d = dst[e];
    int pos = atomicAdd(&cursor[d], 1);
    ssort[pos] = src[e];
  }
}

// Repack (possibly f32) input to bf16 flat.
__global__ void repack_k(const void* in, unsigned short* out, long n, const int* modep){
  int md = *modep;
  long i = (long)blockIdx.x*256 + threadIdx.x;
  if(i<n){
    if(md) out[i] = f2bf(((const float*)in)[i]);
    else   out[i] = ((const unsigned short*)in)[i];
  }
}

// Repack + transpose: in [K][N] -> out [N][K] bf16.
__global__ void repack_t_k(const void* in, unsigned short* out, int K, int N, const int* modep){
  int md = *modep;
  long i = (long)blockIdx.x*256 + threadIdx.x;
  long tot = (long)K*N;
  if(i<tot){
    int k = (int)(i / N), n = (int)(i % N);
    unsigned short v = md ? f2bf(((const float*)in)[i]) : ((const unsigned short*)in)[i];
    out[(long)n*K + k] = v;
  }
}

// C[M,N] f32 = A[M,K]bf16 @ Bt[N,K]bf16^T. 128x128 tile, BK=32, 4 waves.
__global__ __launch_bounds__(256) void gemm_mfma(const unsigned short* A, const unsigned short* Bt,
                                                 float* C, int M, int N, int K){
  __shared__ short As[128*40];
  __shared__ short Bs[128*40];
  int t = threadIdx.x;
  int lane = t & 63, wave = t >> 6;
  int l15 = lane & 15, quad = lane >> 4;
  int wm = (wave>>1)*64, wn = (wave&1)*64;
  int mbase = blockIdx.y*128, nbase = blockIdx.x*128;

  f32x4 acc[4][4];
  #pragma unroll
  for(int i=0;i<4;i++)
    #pragma unroll
    for(int j=0;j<4;j++) acc[i][j] = (f32x4){0.f,0.f,0.f,0.f};

  int c0 = t, c1 = t + 256;
  int row0 = c0>>2, kk0 = (c0&3)*8;
  int row1 = c1>>2, kk1 = (c1&3)*8;
  long arow0 = (long)(mbase+row0)*K, arow1 = (long)(mbase+row1)*K;
  long brow0 = (long)(nbase+row0)*K, brow1 = (long)(nbase+row1)*K;
  bool av0 = (mbase+row0) < M, av1 = (mbase+row1) < M;

  for(int k0=0;k0<K;k0+=32){
    short8 a0 = (short8){0,0,0,0,0,0,0,0}, a1 = a0;
    if(av0) a0 = *(const short8*)(A + arow0 + k0 + kk0);
    if(av1) a1 = *(const short8*)(A + arow1 + k0 + kk1);
    short8 b0 = *(const short8*)(Bt + brow0 + k0 + kk0);
    short8 b1 = *(const short8*)(Bt + brow1 + k0 + kk1);
    __syncthreads();
    *(short8*)(As + row0*40 + kk0) = a0;
    *(short8*)(As + row1*40 + kk1) = a1;
    *(short8*)(Bs + row0*40 + kk0) = b0;
    *(short8*)(Bs + row1*40 + kk1) = b1;
    __syncthreads();
    short8 af[4], bfr[4];
    #pragma unroll
    for(int mi=0;mi<4;mi++) af[mi]  = *(short8*)(As + (wm + mi*16 + l15)*40 + quad*8);
    #pragma unroll
    for(int ni=0;ni<4;ni++) bfr[ni] = *(short8*)(Bs + (wn + ni*16 + l15)*40 + quad*8);
    #pragma unroll
    for(int mi=0;mi<4;mi++)
      #pragma unroll
      for(int ni=0;ni<4;ni++)
        acc[mi][ni] = __builtin_amdgcn_mfma_f32_16x16x32_bf16(af[mi], bfr[ni], acc[mi][ni], 0,0,0);
  }

  #pragma unroll
  for(int mi=0;mi<4;mi++){
    #pragma unroll
    for(int ni=0;ni<4;ni++){
      int grow0 = mbase + wm + mi*16 + quad*4;
      int gcol  = nbase + wn + ni*16 + l15;
      #pragma unroll
      for(int r=0;r<4;r++){
        int grow = grow0 + r;
        if(grow < M) C[(long)grow*N + gcol] = acc[mi][ni][r];
      }
    }
  }
}

// el/er for layer 1 + emit bf16 copy of feat1. Block 512 = 8 waves.
__global__ void dots1_k(const float* feat1, const void* al, const void* ar,
                        float* el, float* er, unsigned short* fb, const int* modep){
  int md = *modep;
  int n = blockIdx.x;
  int hd = threadIdx.x;          // 0..511 = h*64+d
  int h = hd >> 6, d = hd & 63;
  float v = feat1[(long)n*HID + hd];
  fb[(long)n*HID + hd] = f2bf(v);
  float l = v * ldm(al, hd, md);
  float r = v * ldm(ar, hd, md);
  #pragma unroll
  for(int off=32; off>0; off>>=1){ l += __shfl_down(l,off); r += __shfl_down(r,off); }
  if(d==0){ el[n*HEADS+h]=l; er[n*HEADS+h]=r; }
}

// el/er for layer 2 (H=1, D=256) + emit bf16 copy. Block 256.
__global__ void dots2_k(const float* feat2, const void* al, const void* ar,
                        float* el, float* er, unsigned short* fb, const int* modep){
  int md = *modep;
  int n = blockIdx.x, t = threadIdx.x;
  float v = feat2[(long)n*OUT_DIM + t];
  fb[(long)n*OUT_DIM + t] = f2bf(v);
  float l = v * ldm(al, t, md);
  float r = v * ldm(ar, t, md);
  #pragma unroll
  for(int off=32; off>0; off>>=1){ l += __shfl_down(l,off); r += __shfl_down(r,off); }
  __shared__ float sl[4], sr[4];
  int wv = t>>6;
  if((t&63)==0){ sl[wv]=l; sr[wv]=r; }
  __syncthreads();
  if(t==0){ el[n]=sl[0]+sl[1]+sl[2]+sl[3]; er[n]=sr[0]+sr[1]+sr[2]+sr[3]; }
}

// Layer-1 edge softmax + aggregate + ELU -> bf16 x. One block(256) per dst node.
// Gathers bf16 feat rows, 4B/lane (2 cols per thread).
__global__ __launch_bounds__(256) void agg1_k(const unsigned short* fb, const float* el,
                       const float* er, const int* offs, const int* srcs, unsigned short* x){
  int n = blockIdx.x, t = threadIdx.x;
  int off = offs[n];
  int deg = offs[n+1]-off;
  __shared__ float wsum[8], ers[8];
  __shared__ int sidx[CAP];
  __shared__ float wlds[CAP*8];
  if(t<8){ wsum[t]=0.f; ers[t]=er[n*HEADS+t]; }
  bool fits = (deg<=CAP);
  int dcap = fits ? deg : CAP;
  for(int i=t;i<dcap;i+=256) sidx[i]=srcs[off+i];
  __syncthreads();
  // weight pass: thread t's head = t&7 (stride 256 preserves it)
  {
    int tot = deg*HEADS;
    float pw = 0.f;
    int myh = t&7;
    float erh = ers[myh];
    for(int p=t; p<tot; p+=256){
      int i = p>>3;
      int s = fits ? sidx[i] : srcs[off+i];
      float e = el[s*HEADS+myh] + erh;
      e = e>0.f ? e : NEG*e;
      float w = __expf(e);
      if(fits) wlds[p]=w;
      pw += w;
    }
    #pragma unroll
    for(int o=32;o>=8;o>>=1) pw += __shfl_xor(pw,o);
    if((t&63)<8) atomicAdd(&wsum[t&63], pw);
  }
  __syncthreads();
  if(t<8) wsum[t] = wsum[t]>0.f ? 1.f/wsum[t] : 0.f;
  __syncthreads();
  int c0 = 2*t;                 // cols c0, c0+1 (same head)
  int h = c0>>6;
  float inv = wsum[h], ern = ers[h];
  float acc0=0.f, acc1=0.f;
  if(fits){
    #pragma unroll 4
    for(int i=0;i<deg;i++){
      int s = sidx[i];
      float w = wlds[i*8+h];
      unsigned int u = *(const unsigned int*)(fb + (long)s*HID + c0);
      acc0 += w*bflo(u); acc1 += w*bfhi(u);
    }
  } else {
    for(int i=0;i<deg;i++){
      int s = srcs[off+i];
      float e = el[s*HEADS+h]+ern; e = e>0.f?e:NEG*e;
      float w = __expf(e);
      unsigned int u = *(const unsigned int*)(fb + (long)s*HID + c0);
      acc0 += w*bflo(u); acc1 += w*bfhi(u);
    }
  }
  acc0*=inv; acc1*=inv;
  acc0 = acc0>0.f ? acc0 : __expf(acc0)-1.f;   // ELU
  acc1 = acc1>0.f ? acc1 : __expf(acc1)-1.f;
  unsigned int o2 = (unsigned int)f2bf(acc0) | ((unsigned int)f2bf(acc1)<<16);
  *(unsigned int*)(x + (long)n*HID + c0) = o2;
}

// Layer-2 edge softmax + aggregate -> final output. One block(128) per dst node.
__global__ __launch_bounds__(128) void agg2_k(const unsigned short* fb, const float* el,
                       const float* er, const int* offs, const int* srcs, void* out,
                       const int* modep){
  int md = *modep;
  int n = blockIdx.x, t = threadIdx.x;   // 128 threads
  int off = offs[n];
  int deg = offs[n+1]-off;
  __shared__ float wsum1;
  __shared__ int sidx[CAP];
  __shared__ float wlds[CAP];
  if(t==0) wsum1=0.f;
  bool fits = (deg<=CAP);
  int dcap = fits ? deg : CAP;
  for(int i=t;i<dcap;i+=128) sidx[i]=srcs[off+i];
  __syncthreads();
  float ern = er[n];
  float pw = 0.f;
  for(int i=t; i<deg; i+=128){
    int s = fits ? sidx[i] : srcs[off+i];
    float e = el[s]+ern; e = e>0.f ? e : NEG*e;
    float w = __expf(e);
    if(fits) wlds[i]=w;
    pw += w;
  }
  #pragma unroll
  for(int o=32;o>0;o>>=1) pw += __shfl_down(pw,o);
  if((t&63)==0) atomicAdd(&wsum1, pw);
  __syncthreads();
  float inv = wsum1>0.f ? 1.f/wsum1 : 0.f;
  int c0 = 2*t;
  float acc0=0.f, acc1=0.f;
  if(fits){
    #pragma unroll 4
    for(int i=0;i<deg;i++){
      int s = sidx[i];
      float w = wlds[i];
      unsigned int u = *(const unsigned int*)(fb + (long)s*OUT_DIM + c0);
      acc0 += w*bflo(u); acc1 += w*bfhi(u);
    }
  } else {
    for(int i=0;i<deg;i++){
      int s = srcs[off+i];
      float e = el[s]+ern; e=e>0.f?e:NEG*e;
      float w = __expf(e);
      unsigned int u = *(const unsigned int*)(fb + (long)s*OUT_DIM + c0);
      acc0 += w*bflo(u); acc1 += w*bfhi(u);
    }
  }
  acc0*=inv; acc1*=inv;
  long oi = (long)n*OUT_DIM + c0;
  if(md){
    float* fo = (float*)out;
    fo[oi] = acc0; fo[oi+1] = acc1;
  } else {
    unsigned int o2 = (unsigned int)f2bf(acc0) | ((unsigned int)f2bf(acc1)<<16);
    *(unsigned int*)((unsigned short*)out + oi) = o2;
  }
}

extern "C" void kernel_launch(void* const* d_in, const int* in_sizes, int n_in,
                              void* d_out, int out_size, void* d_ws, size_t ws_size,
                              hipStream_t stream){
  (void)n_in; (void)out_size; (void)ws_size;
  const void* h_in = d_in[0];
  const void* W1   = d_in[1];
  const void* al1  = d_in[2];
  const void* ar1  = d_in[3];
  const void* W2   = d_in[4];
  const void* al2  = d_in[5];
  const void* ar2  = d_in[6];
  const int* src = (const int*)d_in[7];
  const int* dst = (const int*)d_in[8];
  int E = in_sizes[7];

  char* ws = (char*)d_ws;
  size_t o = 0;
  auto alloc = [&](size_t b){ size_t c=o; o += (b+255)&~(size_t)255; return c; };
  float* feat1 = (float*)(ws + alloc((size_t)N_NODES*HID*4));
  float* feat2 = (float*)(ws + alloc((size_t)N_NODES*OUT_DIM*4));
  unsigned short* f1b  = (unsigned short*)(ws + alloc((size_t)N_NODES*HID*2));
  unsigned short* f2b  = (unsigned short*)(ws + alloc((size_t)N_NODES*OUT_DIM*2));
  unsigned short* xbuf = (unsigned short*)(ws + alloc((size_t)N_NODES*HID*2));
  unsigned short* abf1 = (unsigned short*)(ws + alloc((size_t)N_NODES*IN_DIM*2));
  unsigned short* wt1  = (unsigned short*)(ws + alloc((size_t)IN_DIM*HID*2));
  unsigned short* wt2  = (unsigned short*)(ws + alloc((size_t)HID*OUT_DIM*2));
  float* el1   = (float*)(ws + alloc((size_t)N_NODES*HEADS*4));
  float* er1   = (float*)(ws + alloc((size_t)N_NODES*HEADS*4));
  int* offs    = (int*)(ws + alloc((size_t)(N_NODES+1)*4));
  int* cursor  = (int*)(ws + alloc((size_t)N_NODES*4));
  int* ssort   = (int*)(ws + alloc((size_t)E*4));
  int* modep   = (int*)(ws + alloc(256));
  float* el2 = el1;   // el1 dead after agg1
  float* er2 = er1;

  hipMemsetAsync(cursor, 0, N_NODES*4, stream);
  detect_k<<<1,256,0,stream>>>((const unsigned short*)W1, modep);
  hist_k<<<(E+255)/256,256,0,stream>>>(dst, cursor, E);
  scan_k<<<1,1024,0,stream>>>(cursor, offs, cursor, N_NODES);
  scatter_k<<<(E+255)/256,256,0,stream>>>(src, dst, cursor, ssort, E);

  {
    long n1 = (long)N_NODES*IN_DIM;
    repack_k<<<(int)((n1+255)/256),256,0,stream>>>(h_in, abf1, n1, modep);
    long nw1 = (long)IN_DIM*HID;
    repack_t_k<<<(int)((nw1+255)/256),256,0,stream>>>(W1, wt1, IN_DIM, HID, modep);
    long nw2 = (long)HID*OUT_DIM;
    repack_t_k<<<(int)((nw2+255)/256),256,0,stream>>>(W2, wt2, HID, OUT_DIM, modep);
  }

  // layer 1
  gemm_mfma<<<dim3(HID/128,(N_NODES+127)/128),256,0,stream>>>(
      abf1, wt1, feat1, N_NODES, HID, IN_DIM);
  dots1_k<<<N_NODES,512,0,stream>>>(feat1, al1, ar1, el1, er1, f1b, modep);
  agg1_k<<<N_NODES,256,0,stream>>>(f1b, el1, er1, offs, ssort, xbuf);

  // layer 2
  gemm_mfma<<<dim3(OUT_DIM/128,(N_NODES+127)/128),256,0,stream>>>(
      xbuf, wt2, feat2, N_NODES, OUT_DIM, HID);
  dots2_k<<<N_NODES,256,0,stream>>>(feat2, al2, ar2, el2, er2, f2b, modep);
  agg2_k<<<N_NODES,128,0,stream>>>(f2b, el2, er2, offs, ssort, d_out, modep);
}

// Round 4
// 235.076 us; speedup vs baseline: 1.9784x; 1.0821x over previous
//
#include <hip/hip_runtime.h>
#include <hip/hip_bf16.h>

#define N_NODES 10000
#define IN_DIM 256
#define HID 512      // HEADS*HIDDEN
#define HEADS 8
#define OUT_DIM 256
#define NEG 0.2f
#define CAP 512      // max cached degree per node (actual max ~70)

typedef __hip_bfloat16 bf16;
typedef __attribute__((ext_vector_type(8))) short short8;
typedef __attribute__((ext_vector_type(4))) float f32x4;

// mode==1 -> data is fp32; mode==0 -> data is bf16
__device__ __forceinline__ float ldm(const void* p, long i, int mode){
  if(mode) return ((const float*)p)[i];
  return __bfloat162float(((const bf16*)p)[i]);
}
__device__ __forceinline__ unsigned short f2bf(float f){
  bf16 b = __float2bfloat16(f);
  return *(unsigned short*)&b;
}
__device__ __forceinline__ float bflo(unsigned int u){ return __uint_as_float(u<<16); }
__device__ __forceinline__ float bfhi(unsigned int u){ return __uint_as_float(u&0xffff0000u); }

// block 0: sniff bf16-vs-f32; blocks 1..: zero the histogram counters.
__global__ void detect_zero_k(const unsigned short* w1raw, int* mode, int* cnt){
  int t = threadIdx.x;
  if(blockIdx.x==0){
    __shared__ int sbad;
    if(t==0) sbad=0;
    __syncthreads();
    int bad=0;
    for(int i=t;i<512;i+=256){
      unsigned int u = ((unsigned int)w1raw[i])<<16;
      float f = __uint_as_float(u);
      if(!(f==f) || fabsf(f) > 100.0f) bad++;
    }
    #pragma unroll
    for(int o=32;o>0;o>>=1) bad += __shfl_down(bad,o);
    if((t&63)==0) atomicAdd(&sbad, bad);
    __syncthreads();
    if(t==0) *mode = (sbad>10) ? 1 : 0;
  } else {
    int i = (blockIdx.x-1)*256 + t;
    if(i<N_NODES) cnt[i]=0;
  }
}

__global__ void hist_k(const int* dst, int* cnt, int E){
  int e = blockIdx.x*256 + threadIdx.x;
  if(e<E) atomicAdd(&cnt[dst[e]], 1);
}

// single-block scan: 1024 threads x 10-node serial chunks.
__global__ void scan_k(const int* counts, int* offsets, int* cursor, int n){
  __shared__ int tmp[1024];
  const int CH = 10;
  int t = threadIdx.x;
  int base = t*CH;
  int loc[CH];
  int s = 0;
  #pragma unroll
  for(int i=0;i<CH;i++){
    int idx = base+i;
    int v = (idx<n) ? counts[idx] : 0;
    loc[i] = s; s += v;
  }
  tmp[t] = s;
  __syncthreads();
  for(int off=1; off<1024; off<<=1){
    int u = (t>=off) ? tmp[t-off] : 0;
    __syncthreads();
    tmp[t] += u;
    __syncthreads();
  }
  int excl = tmp[t] - s;
  #pragma unroll
  for(int i=0;i<CH;i++){
    int idx = base+i;
    if(idx<n){ int o = excl + loc[i]; offsets[idx]=o; cursor[idx]=o; }
  }
  if(t==1023) offsets[n] = tmp[1023];
}

__global__ void scatter_k(const int* src, const int* dst, int* cursor, int* ssort, int E){
  int e = blockIdx.x*256 + threadIdx.x;
  if(e<E){
    int d = dst[e];
    int pos = atomicAdd(&cursor[d], 1);
    ssort[pos] = src[e];
  }
}

// Both weight transposes in one kernel: W1[K1][HID]->wt1[HID][K1], W2[K2][OUT]->wt2[OUT][K2].
__global__ void wprep_k(const void* W1, const void* W2, unsigned short* wt1,
                        unsigned short* wt2, const int* modep){
  int md = *modep;
  long i = (long)blockIdx.x*256 + threadIdx.x;
  const long n1 = (long)IN_DIM*HID;
  if(i < n1){
    int k = (int)(i/HID), n = (int)(i%HID);
    unsigned short v = md ? f2bf(((const float*)W1)[i]) : ((const unsigned short*)W1)[i];
    wt1[(long)n*IN_DIM + k] = v;
  } else {
    long j = i - n1;   // < HID*OUT_DIM
    int k = (int)(j/OUT_DIM), n = (int)(j%OUT_DIM);
    unsigned short v = md ? f2bf(((const float*)W2)[j]) : ((const unsigned short*)W2)[j];
    wt2[(long)n*HID + k] = v;
  }
}

// C[M,N]bf16 = A[M,K] @ Bt[N,K]^T (bf16 MFMA). A is bf16, or f32 when
// asel&&*modep (converted during staging). 128x128 tile, BK=32, 4 waves.
__global__ __launch_bounds__(256) void gemm_k(const void* A, const unsigned short* Bt,
                                              unsigned short* C, int M, int N, int K,
                                              int asel, const int* modep){
  int am = asel ? *modep : 0;   // 1 -> A is f32
  __shared__ short As[128*40];
  __shared__ short Bs[128*40];
  int t = threadIdx.x;
  int lane = t & 63, wave = t >> 6;
  int l15 = lane & 15, quad = lane >> 4;
  int wm = (wave>>1)*64, wn = (wave&1)*64;
  int mbase = blockIdx.y*128, nbase = blockIdx.x*128;

  f32x4 acc[4][4];
  #pragma unroll
  for(int i=0;i<4;i++)
    #pragma unroll
    for(int j=0;j<4;j++) acc[i][j] = (f32x4){0.f,0.f,0.f,0.f};

  int c0 = t, c1 = t + 256;
  int row0 = c0>>2, kk0 = (c0&3)*8;
  int row1 = c1>>2, kk1 = (c1&3)*8;
  long arow0 = (long)(mbase+row0)*K, arow1 = (long)(mbase+row1)*K;
  long brow0 = (long)(nbase+row0)*K, brow1 = (long)(nbase+row1)*K;
  bool av0 = (mbase+row0) < M, av1 = (mbase+row1) < M;
  const unsigned short* Ab = (const unsigned short*)A;
  const float* Af = (const float*)A;

  for(int k0=0;k0<K;k0+=32){
    short8 a0 = (short8){0,0,0,0,0,0,0,0}, a1 = a0;
    if(am){
      if(av0){
        float4 x = *(const float4*)(Af + arow0 + k0 + kk0);
        float4 y = *(const float4*)(Af + arow0 + k0 + kk0 + 4);
        a0[0]=f2bf(x.x); a0[1]=f2bf(x.y); a0[2]=f2bf(x.z); a0[3]=f2bf(x.w);
        a0[4]=f2bf(y.x); a0[5]=f2bf(y.y); a0[6]=f2bf(y.z); a0[7]=f2bf(y.w);
      }
      if(av1){
        float4 x = *(const float4*)(Af + arow1 + k0 + kk1);
        float4 y = *(const float4*)(Af + arow1 + k0 + kk1 + 4);
        a1[0]=f2bf(x.x); a1[1]=f2bf(x.y); a1[2]=f2bf(x.z); a1[3]=f2bf(x.w);
        a1[4]=f2bf(y.x); a1[5]=f2bf(y.y); a1[6]=f2bf(y.z); a1[7]=f2bf(y.w);
      }
    } else {
      if(av0) a0 = *(const short8*)(Ab + arow0 + k0 + kk0);
      if(av1) a1 = *(const short8*)(Ab + arow1 + k0 + kk1);
    }
    short8 b0 = *(const short8*)(Bt + brow0 + k0 + kk0);
    short8 b1 = *(const short8*)(Bt + brow1 + k0 + kk1);
    __syncthreads();
    *(short8*)(As + row0*40 + kk0) = a0;
    *(short8*)(As + row1*40 + kk1) = a1;
    *(short8*)(Bs + row0*40 + kk0) = b0;
    *(short8*)(Bs + row1*40 + kk1) = b1;
    __syncthreads();
    short8 af[4], bfr[4];
    #pragma unroll
    for(int mi=0;mi<4;mi++) af[mi]  = *(short8*)(As + (wm + mi*16 + l15)*40 + quad*8);
    #pragma unroll
    for(int ni=0;ni<4;ni++) bfr[ni] = *(short8*)(Bs + (wn + ni*16 + l15)*40 + quad*8);
    #pragma unroll
    for(int mi=0;mi<4;mi++)
      #pragma unroll
      for(int ni=0;ni<4;ni++)
        acc[mi][ni] = __builtin_amdgcn_mfma_f32_16x16x32_bf16(af[mi], bfr[ni], acc[mi][ni], 0,0,0);
  }

  #pragma unroll
  for(int mi=0;mi<4;mi++){
    #pragma unroll
    for(int ni=0;ni<4;ni++){
      int grow0 = mbase + wm + mi*16 + quad*4;
      int gcol  = nbase + wn + ni*16 + l15;
      #pragma unroll
      for(int r=0;r<4;r++){
        int grow = grow0 + r;
        if(grow < M) C[(long)grow*N + gcol] = f2bf(acc[mi][ni][r]);
      }
    }
  }
}

// el/er for layer 1 from bf16 feat. Block 256, 2 cols/thread (u32 loads).
__global__ void dots1_k(const unsigned short* fb, const void* al, const void* ar,
                        float* el, float* er, const int* modep){
  int md = *modep;
  int n = blockIdx.x, t = threadIdx.x;
  int c = 2*t;                       // cols c, c+1 (same head; head = t>>5)
  unsigned int u = *(const unsigned int*)(fb + (long)n*HID + c);
  float v0 = bflo(u), v1 = bfhi(u);
  float l = v0*ldm(al,c,md) + v1*ldm(al,c+1,md);
  float r = v0*ldm(ar,c,md) + v1*ldm(ar,c+1,md);
  #pragma unroll
  for(int o=16;o>0;o>>=1){ l += __shfl_xor(l,o); r += __shfl_xor(r,o); }
  if((t&31)==0){ int h = t>>5; el[n*HEADS+h]=l; er[n*HEADS+h]=r; }
}

// el/er for layer 2 (H=1, D=256) from bf16 feat. Block 128, 2 cols/thread.
__global__ void dots2_k(const unsigned short* fb, const void* al, const void* ar,
                        float* el, float* er, const int* modep){
  int md = *modep;
  int n = blockIdx.x, t = threadIdx.x;
  int c = 2*t;
  unsigned int u = *(const unsigned int*)(fb + (long)n*OUT_DIM + c);
  float v0 = bflo(u), v1 = bfhi(u);
  float l = v0*ldm(al,c,md) + v1*ldm(al,c+1,md);
  float r = v0*ldm(ar,c,md) + v1*ldm(ar,c+1,md);
  #pragma unroll
  for(int o=32;o>0;o>>=1){ l += __shfl_xor(l,o); r += __shfl_xor(r,o); }
  __shared__ float sl[2], sr[2];
  if((t&63)==0){ sl[t>>6]=l; sr[t>>6]=r; }
  __syncthreads();
  if(t==0){ el[n]=sl[0]+sl[1]; er[n]=sr[0]+sr[1]; }
}

// Layer-1 edge softmax + aggregate + ELU -> bf16 x. One block(256) per dst node.
__global__ __launch_bounds__(256) void agg1_k(const unsigned short* fb, const float* el,
                       const float* er, const int* offs, const int* srcs, unsigned short* x){
  int n = blockIdx.x, t = threadIdx.x;
  int off = offs[n];
  int deg = offs[n+1]-off;
  __shared__ float wsum[8], ers[8];
  __shared__ int sidx[CAP];
  __shared__ float wlds[CAP*8];
  if(t<8){ wsum[t]=0.f; ers[t]=er[n*HEADS+t]; }
  bool fits = (deg<=CAP);
  int dcap = fits ? deg : CAP;
  for(int i=t;i<dcap;i+=256) sidx[i]=srcs[off+i];
  __syncthreads();
  {
    int tot = deg*HEADS;
    float pw = 0.f;
    int myh = t&7;
    float erh = ers[myh];
    for(int p=t; p<tot; p+=256){
      int i = p>>3;
      int s = fits ? sidx[i] : srcs[off+i];
      float e = el[s*HEADS+myh] + erh;
      e = e>0.f ? e : NEG*e;
      float w = __expf(e);
      if(fits) wlds[p]=w;
      pw += w;
    }
    #pragma unroll
    for(int o=32;o>=8;o>>=1) pw += __shfl_xor(pw,o);
    if((t&63)<8) atomicAdd(&wsum[t&63], pw);
  }
  __syncthreads();
  if(t<8) wsum[t] = wsum[t]>0.f ? 1.f/wsum[t] : 0.f;
  __syncthreads();
  int c0 = 2*t;
  int h = c0>>6;
  float inv = wsum[h], ern = ers[h];
  float acc0=0.f, acc1=0.f;
  if(fits){
    #pragma unroll 8
    for(int i=0;i<deg;i++){
      int s = sidx[i];
      float w = wlds[i*8+h];
      unsigned int u = *(const unsigned int*)(fb + (long)s*HID + c0);
      acc0 += w*bflo(u); acc1 += w*bfhi(u);
    }
  } else {
    for(int i=0;i<deg;i++){
      int s = srcs[off+i];
      float e = el[s*HEADS+h]+ern; e = e>0.f?e:NEG*e;
      float w = __expf(e);
      unsigned int u = *(const unsigned int*)(fb + (long)s*HID + c0);
      acc0 += w*bflo(u); acc1 += w*bfhi(u);
    }
  }
  acc0*=inv; acc1*=inv;
  acc0 = acc0>0.f ? acc0 : __expf(acc0)-1.f;   // ELU
  acc1 = acc1>0.f ? acc1 : __expf(acc1)-1.f;
  unsigned int o2 = (unsigned int)f2bf(acc0) | ((unsigned int)f2bf(acc1)<<16);
  *(unsigned int*)(x + (long)n*HID + c0) = o2;
}

// Layer-2 edge softmax + aggregate -> final output. One block(128) per dst node.
__global__ __launch_bounds__(128) void agg2_k(const unsigned short* fb, const float* el,
                       const float* er, const int* offs, const int* srcs, void* out,
                       const int* modep){
  int md = *modep;
  int n = blockIdx.x, t = threadIdx.x;
  int off = offs[n];
  int deg = offs[n+1]-off;
  __shared__ float wsum1;
  __shared__ int sidx[CAP];
  __shared__ float wlds[CAP];
  if(t==0) wsum1=0.f;
  bool fits = (deg<=CAP);
  int dcap = fits ? deg : CAP;
  for(int i=t;i<dcap;i+=128) sidx[i]=srcs[off+i];
  __syncthreads();
  float ern = er[n];
  float pw = 0.f;
  for(int i=t; i<deg; i+=128){
    int s = fits ? sidx[i] : srcs[off+i];
    float e = el[s]+ern; e = e>0.f ? e : NEG*e;
    float w = __expf(e);
    if(fits) wlds[i]=w;
    pw += w;
  }
  #pragma unroll
  for(int o=32;o>0;o>>=1) pw += __shfl_down(pw,o);
  if((t&63)==0) atomicAdd(&wsum1, pw);
  __syncthreads();
  float inv = wsum1>0.f ? 1.f/wsum1 : 0.f;
  int c0 = 2*t;
  float acc0=0.f, acc1=0.f;
  if(fits){
    #pragma unroll 8
    for(int i=0;i<deg;i++){
      int s = sidx[i];
      float w = wlds[i];
      unsigned int u = *(const unsigned int*)(fb + (long)s*OUT_DIM + c0);
      acc0 += w*bflo(u); acc1 += w*bfhi(u);
    }
  } else {
    for(int i=0;i<deg;i++){
      int s = srcs[off+i];
      float e = el[s]+ern; e=e>0.f?e:NEG*e;
      float w = __expf(e);
      unsigned int u = *(const unsigned int*)(fb + (long)s*OUT_DIM + c0);
      acc0 += w*bflo(u); acc1 += w*bfhi(u);
    }
  }
  acc0*=inv; acc1*=inv;
  long oi = (long)n*OUT_DIM + c0;
  if(md){
    float* fo = (float*)out;
    fo[oi] = acc0; fo[oi+1] = acc1;
  } else {
    unsigned int o2 = (unsigned int)f2bf(acc0) | ((unsigned int)f2bf(acc1)<<16);
    *(unsigned int*)((unsigned short*)out + oi) = o2;
  }
}

extern "C" void kernel_launch(void* const* d_in, const int* in_sizes, int n_in,
                              void* d_out, int out_size, void* d_ws, size_t ws_size,
                              hipStream_t stream){
  (void)n_in; (void)out_size; (void)ws_size;
  const void* h_in = d_in[0];
  const void* W1   = d_in[1];
  const void* al1  = d_in[2];
  const void* ar1  = d_in[3];
  const void* W2   = d_in[4];
  const void* al2  = d_in[5];
  const void* ar2  = d_in[6];
  const int* src = (const int*)d_in[7];
  const int* dst = (const int*)d_in[8];
  int E = in_sizes[7];

  char* ws = (char*)d_ws;
  size_t o = 0;
  auto alloc = [&](size_t b){ size_t c=o; o += (b+255)&~(size_t)255; return c; };
  unsigned short* f1b  = (unsigned short*)(ws + alloc((size_t)N_NODES*HID*2));
  unsigned short* f2b  = (unsigned short*)(ws + alloc((size_t)N_NODES*OUT_DIM*2));
  unsigned short* xbuf = (unsigned short*)(ws + alloc((size_t)N_NODES*HID*2));
  unsigned short* wt1  = (unsigned short*)(ws + alloc((size_t)IN_DIM*HID*2));
  unsigned short* wt2  = (unsigned short*)(ws + alloc((size_t)HID*OUT_DIM*2));
  float* el1   = (float*)(ws + alloc((size_t)N_NODES*HEADS*4));
  float* er1   = (float*)(ws + alloc((size_t)N_NODES*HEADS*4));
  int* offs    = (int*)(ws + alloc((size_t)(N_NODES+1)*4));
  int* cursor  = (int*)(ws + alloc((size_t)N_NODES*4));
  int* ssort   = (int*)(ws + alloc((size_t)E*4));
  int* modep   = (int*)(ws + alloc(256));
  float* el2 = el1;   // el1 dead after agg1
  float* er2 = er1;

  detect_zero_k<<<1+(N_NODES+255)/256,256,0,stream>>>((const unsigned short*)W1, modep, cursor);
  hist_k<<<(E+255)/256,256,0,stream>>>(dst, cursor, E);
  scan_k<<<1,1024,0,stream>>>(cursor, offs, cursor, N_NODES);
  scatter_k<<<(E+255)/256,256,0,stream>>>(src, dst, cursor, ssort, E);
  wprep_k<<<(int)(((long)IN_DIM*HID+(long)HID*OUT_DIM)/256),256,0,stream>>>(W1, W2, wt1, wt2, modep);

  // layer 1
  gemm_k<<<dim3(HID/128,(N_NODES+127)/128),256,0,stream>>>(
      h_in, wt1, f1b, N_NODES, HID, IN_DIM, 1, modep);
  dots1_k<<<N_NODES,256,0,stream>>>(f1b, al1, ar1, el1, er1, modep);
  agg1_k<<<N_NODES,256,0,stream>>>(f1b, el1, er1, offs, ssort, xbuf);

  // layer 2
  gemm_k<<<dim3(OUT_DIM/128,(N_NODES+127)/128),256,0,stream>>>(
      xbuf, wt2, f2b, N_NODES, OUT_DIM, HID, 0, modep);
  dots2_k<<<N_NODES,128,0,stream>>>(f2b, al2, ar2, el2, er2, modep);
  agg2_k<<<N_NODES,128,0,stream>>>(f2b, el2, er2, offs, ssort, d_out, modep);
}

// Round 5
// 199.210 us; speedup vs baseline: 2.3346x; 1.1800x over previous
//
#include <hip/hip_runtime.h>
#include <hip/hip_bf16.h>

#define N_NODES 10000
#define IN_DIM 256
#define HID 512      // HEADS*HIDDEN
#define HEADS 8
#define OUT_DIM 256
#define NEG 0.2f
#define CAP 512      // bucket capacity per node (actual max deg ~70)

typedef __hip_bfloat16 bf16;
typedef __attribute__((ext_vector_type(8))) short short8;
typedef __attribute__((ext_vector_type(4))) float f32x4;

__device__ __forceinline__ float ldm(const void* p, long i, int mode){
  if(mode) return ((const float*)p)[i];
  return __bfloat162float(((const bf16*)p)[i]);
}
__device__ __forceinline__ unsigned short f2bf(float f){
  bf16 b = __float2bfloat16(f);
  return *(unsigned short*)&b;
}
__device__ __forceinline__ float bflo(unsigned int u){ return __uint_as_float(u<<16); }
__device__ __forceinline__ float bfhi(unsigned int u){ return __uint_as_float(u&0xffff0000u); }

// block 0: sniff bf16-vs-f32. blocks 1..: zero cnt + el/er accumulators.
__global__ void detect_zero_k(const unsigned short* w1raw, int* mode, int* cnt,
                              float* el1, float* er1, float* el2, float* er2){
  int t = threadIdx.x;
  if(blockIdx.x==0){
    __shared__ int sbad;
    if(t==0) sbad=0;
    __syncthreads();
    int bad=0;
    for(int i=t;i<512;i+=256){
      unsigned int u = ((unsigned int)w1raw[i])<<16;
      float f = __uint_as_float(u);
      if(!(f==f) || fabsf(f) > 100.0f) bad++;
    }
    #pragma unroll
    for(int o=32;o>0;o>>=1) bad += __shfl_down(bad,o);
    if((t&63)==0) atomicAdd(&sbad, bad);
    __syncthreads();
    if(t==0) *mode = (sbad>10) ? 1 : 0;
  } else {
    int i = (blockIdx.x-1)*256 + t;   // covers [0, 80000)
    if(i<N_NODES*HEADS){ el1[i]=0.f; er1[i]=0.f; }
    if(i<N_NODES){ cnt[i]=0; el2[i]=0.f; er2[i]=0.f; }
  }
}

// bucketed CSR build: one pass, no hist/scan.
__global__ void scatter_k(const int* src, const int* dst, int* cnt, int* bucket, int E){
  int e = blockIdx.x*256 + threadIdx.x;
  if(e<E){
    int d = dst[e];
    int pos = atomicAdd(&cnt[d], 1);
    if(pos < CAP) bucket[(long)d*CAP + pos] = src[e];
  }
}

// Both weight transposes: W1[K1][HID]->wt1[HID][K1], W2[K2][OUT]->wt2[OUT][K2].
__global__ void wprep_k(const void* W1, const void* W2, unsigned short* wt1,
                        unsigned short* wt2, const int* modep){
  int md = *modep;
  long i = (long)blockIdx.x*256 + threadIdx.x;
  const long n1 = (long)IN_DIM*HID;
  if(i < n1){
    int k = (int)(i/HID), n = (int)(i%HID);
    unsigned short v = md ? f2bf(((const float*)W1)[i]) : ((const unsigned short*)W1)[i];
    wt1[(long)n*IN_DIM + k] = v;
  } else {
    long j = i - n1;
    int k = (int)(j/OUT_DIM), n = (int)(j%OUT_DIM);
    unsigned short v = md ? f2bf(((const float*)W2)[j]) : ((const unsigned short*)W2)[j];
    wt2[(long)n*HID + k] = v;
  }
}

// C[M,N]bf16 = A[M,K] @ Bt[N,K]^T with fused attention-dot epilogue.
// 64x64 tile, BK=32, 4 waves (each 32x32 = 2x2 16x16x32 frags).
// dmode==1: el stride 8, head = nbase>>6 (layer1). dmode==2: el stride 1 (layer2).
__global__ __launch_bounds__(256) void gemm_k(const void* A, const unsigned short* Bt,
                                              unsigned short* C, int M, int N, int K,
                                              int asel, const int* modep,
                                              const void* al, const void* ar,
                                              float* el, float* er, int dmode){
  int md = *modep;
  int am = asel ? md : 0;   // 1 -> A is f32
  __shared__ short As[64*40];
  __shared__ short Bs[64*40];
  __shared__ float led[64], ler[64];
  int t = threadIdx.x;
  int lane = t & 63, wave = t >> 6;
  int l15 = lane & 15, quad = lane >> 4;
  int wm = (wave>>1)*32, wn = (wave&1)*32;
  int mbase = blockIdx.y*64, nbase = blockIdx.x*64;

  f32x4 acc[2][2];
  #pragma unroll
  for(int i=0;i<2;i++)
    #pragma unroll
    for(int j=0;j<2;j++) acc[i][j] = (f32x4){0.f,0.f,0.f,0.f};

  int row = t>>2, kk = (t&3)*8;
  long arow = (long)(mbase+row)*K, brow = (long)(nbase+row)*K;
  bool av = (mbase+row) < M;
  const unsigned short* Ab = (const unsigned short*)A;
  const float* Af = (const float*)A;

  for(int k0=0;k0<K;k0+=32){
    short8 a = (short8){0,0,0,0,0,0,0,0};
    if(am){
      if(av){
        float4 x = *(const float4*)(Af + arow + k0 + kk);
        float4 y = *(const float4*)(Af + arow + k0 + kk + 4);
        a[0]=f2bf(x.x); a[1]=f2bf(x.y); a[2]=f2bf(x.z); a[3]=f2bf(x.w);
        a[4]=f2bf(y.x); a[5]=f2bf(y.y); a[6]=f2bf(y.z); a[7]=f2bf(y.w);
      }
    } else {
      if(av) a = *(const short8*)(Ab + arow + k0 + kk);
    }
    short8 b = *(const short8*)(Bt + brow + k0 + kk);
    __syncthreads();
    *(short8*)(As + row*40 + kk) = a;
    *(short8*)(Bs + row*40 + kk) = b;
    __syncthreads();
    short8 af[2], bfr[2];
    #pragma unroll
    for(int mi=0;mi<2;mi++) af[mi]  = *(short8*)(As + (wm + mi*16 + l15)*40 + quad*8);
    #pragma unroll
    for(int ni=0;ni<2;ni++) bfr[ni] = *(short8*)(Bs + (wn + ni*16 + l15)*40 + quad*8);
    #pragma unroll
    for(int mi=0;mi<2;mi++)
      #pragma unroll
      for(int ni=0;ni<2;ni++)
        acc[mi][ni] = __builtin_amdgcn_mfma_f32_16x16x32_bf16(af[mi], bfr[ni], acc[mi][ni], 0,0,0);
  }

  // C store (bf16)
  #pragma unroll
  for(int mi=0;mi<2;mi++){
    #pragma unroll
    for(int ni=0;ni<2;ni++){
      int grow0 = mbase + wm + mi*16 + quad*4;
      int gcol  = nbase + wn + ni*16 + l15;
      #pragma unroll
      for(int r=0;r<4;r++){
        int grow = grow0 + r;
        if(grow < M) C[(long)grow*N + gcol] = f2bf(acc[mi][ni][r]);
      }
    }
  }

  // fused dots epilogue: partial el/er for this block's 64 rows
  float avv[2], rvv[2];
  #pragma unroll
  for(int ni=0;ni<2;ni++){
    int gc = nbase + wn + ni*16 + l15;
    avv[ni] = ldm(al, gc, md);
    rvv[ni] = ldm(ar, gc, md);
  }
  __syncthreads();
  if(t<64){ led[t]=0.f; ler[t]=0.f; }
  __syncthreads();
  #pragma unroll
  for(int mi=0;mi<2;mi++){
    #pragma unroll
    for(int r=0;r<4;r++){
      float pl = acc[mi][0][r]*avv[0] + acc[mi][1][r]*avv[1];
      float pr = acc[mi][0][r]*rvv[0] + acc[mi][1][r]*rvv[1];
      #pragma unroll
      for(int o=1;o<16;o<<=1){ pl += __shfl_xor(pl,o); pr += __shfl_xor(pr,o); }
      if(l15==0){
        int lr = wm + mi*16 + quad*4 + r;
        atomicAdd(&led[lr], pl);
        atomicAdd(&ler[lr], pr);
      }
    }
  }
  __syncthreads();
  if(t<64){
    int grow = mbase + t;
    if(grow < M){
      int estride = (dmode==1) ? HEADS : 1;
      int hidx    = (dmode==1) ? (nbase>>6) : 0;
      atomicAdd(&el[(long)grow*estride + hidx], led[t]);
      atomicAdd(&er[(long)grow*estride + hidx], ler[t]);
    }
  }
}

// Layer-1 edge softmax + aggregate + ELU -> bf16 x. One block(256) per dst node.
__global__ __launch_bounds__(256) void agg1_k(const unsigned short* fb, const float* el,
                       const float* er, const int* cnt, const int* bucket, unsigned short* x){
  int n = blockIdx.x, t = threadIdx.x;
  long off = (long)n*CAP;
  int deg = cnt[n]; if(deg>CAP) deg=CAP;
  __shared__ float wsum[8], ers[8];
  __shared__ int sidx[CAP];
  __shared__ float wlds[CAP*8];
  if(t<8){ wsum[t]=0.f; ers[t]=er[n*HEADS+t]; }
  for(int i=t;i<deg;i+=256) sidx[i]=bucket[off+i];
  __syncthreads();
  {
    int tot = deg*HEADS;
    float pw = 0.f;
    int myh = t&7;
    float erh = ers[myh];
    for(int p=t; p<tot; p+=256){
      int i = p>>3;
      int s = sidx[i];
      float e = el[s*HEADS+myh] + erh;
      e = e>0.f ? e : NEG*e;
      float w = __expf(e);
      wlds[p]=w;
      pw += w;
    }
    #pragma unroll
    for(int o=32;o>=8;o>>=1) pw += __shfl_xor(pw,o);
    if((t&63)<8) atomicAdd(&wsum[t&63], pw);
  }
  __syncthreads();
  if(t<8) wsum[t] = wsum[t]>0.f ? 1.f/wsum[t] : 0.f;
  __syncthreads();
  int c0 = 2*t;
  int h = c0>>6;
  float inv = wsum[h];
  float acc0=0.f, acc1=0.f;
  #pragma unroll 8
  for(int i=0;i<deg;i++){
    int s = sidx[i];
    float w = wlds[i*8+h];
    unsigned int u = *(const unsigned int*)(fb + (long)s*HID + c0);
    acc0 += w*bflo(u); acc1 += w*bfhi(u);
  }
  acc0*=inv; acc1*=inv;
  acc0 = acc0>0.f ? acc0 : __expf(acc0)-1.f;   // ELU
  acc1 = acc1>0.f ? acc1 : __expf(acc1)-1.f;
  unsigned int o2 = (unsigned int)f2bf(acc0) | ((unsigned int)f2bf(acc1)<<16);
  *(unsigned int*)(x + (long)n*HID + c0) = o2;
}

// Layer-2 edge softmax + aggregate -> final output. One block(128) per dst node.
__global__ __launch_bounds__(128) void agg2_k(const unsigned short* fb, const float* el,
                       const float* er, const int* cnt, const int* bucket, void* out,
                       const int* modep){
  int md = *modep;
  int n = blockIdx.x, t = threadIdx.x;
  long off = (long)n*CAP;
  int deg = cnt[n]; if(deg>CAP) deg=CAP;
  __shared__ float wsum1;
  __shared__ int sidx[CAP];
  __shared__ float wlds[CAP];
  if(t==0) wsum1=0.f;
  for(int i=t;i<deg;i+=128) sidx[i]=bucket[off+i];
  __syncthreads();
  float ern = er[n];
  float pw = 0.f;
  for(int i=t; i<deg; i+=128){
    int s = sidx[i];
    float e = el[s]+ern; e = e>0.f ? e : NEG*e;
    float w = __expf(e);
    wlds[i]=w;
    pw += w;
  }
  #pragma unroll
  for(int o=32;o>0;o>>=1) pw += __shfl_down(pw,o);
  if((t&63)==0) atomicAdd(&wsum1, pw);
  __syncthreads();
  float inv = wsum1>0.f ? 1.f/wsum1 : 0.f;
  int c0 = 2*t;
  float acc0=0.f, acc1=0.f;
  #pragma unroll 8
  for(int i=0;i<deg;i++){
    int s = sidx[i];
    float w = wlds[i];
    unsigned int u = *(const unsigned int*)(fb + (long)s*OUT_DIM + c0);
    acc0 += w*bflo(u); acc1 += w*bfhi(u);
  }
  acc0*=inv; acc1*=inv;
  long oi = (long)n*OUT_DIM + c0;
  if(md){
    float* fo = (float*)out;
    fo[oi] = acc0; fo[oi+1] = acc1;
  } else {
    unsigned int o2 = (unsigned int)f2bf(acc0) | ((unsigned int)f2bf(acc1)<<16);
    *(unsigned int*)((unsigned short*)out + oi) = o2;
  }
}

extern "C" void kernel_launch(void* const* d_in, const int* in_sizes, int n_in,
                              void* d_out, int out_size, void* d_ws, size_t ws_size,
                              hipStream_t stream){
  (void)n_in; (void)out_size; (void)ws_size;
  const void* h_in = d_in[0];
  const void* W1   = d_in[1];
  const void* al1  = d_in[2];
  const void* ar1  = d_in[3];
  const void* W2   = d_in[4];
  const void* al2  = d_in[5];
  const void* ar2  = d_in[6];
  const int* src = (const int*)d_in[7];
  const int* dst = (const int*)d_in[8];
  int E = in_sizes[7];

  char* ws = (char*)d_ws;
  size_t o = 0;
  auto alloc = [&](size_t b){ size_t c=o; o += (b+255)&~(size_t)255; return c; };
  unsigned short* f1b  = (unsigned short*)(ws + alloc((size_t)N_NODES*HID*2));
  unsigned short* f2b  = (unsigned short*)(ws + alloc((size_t)N_NODES*OUT_DIM*2));
  unsigned short* xbuf = (unsigned short*)(ws + alloc((size_t)N_NODES*HID*2));
  unsigned short* wt1  = (unsigned short*)(ws + alloc((size_t)IN_DIM*HID*2));
  unsigned short* wt2  = (unsigned short*)(ws + alloc((size_t)HID*OUT_DIM*2));
  float* el1   = (float*)(ws + alloc((size_t)N_NODES*HEADS*4));
  float* er1   = (float*)(ws + alloc((size_t)N_NODES*HEADS*4));
  float* el2   = (float*)(ws + alloc((size_t)N_NODES*4));
  float* er2   = (float*)(ws + alloc((size_t)N_NODES*4));
  int* cnt     = (int*)(ws + alloc((size_t)N_NODES*4));
  int* bucket  = (int*)(ws + alloc((size_t)N_NODES*CAP*4));
  int* modep   = (int*)(ws + alloc(256));

  detect_zero_k<<<1+(N_NODES*HEADS+255)/256,256,0,stream>>>(
      (const unsigned short*)W1, modep, cnt, el1, er1, el2, er2);
  scatter_k<<<(E+255)/256,256,0,stream>>>(src, dst, cnt, bucket, E);
  wprep_k<<<(int)(((long)IN_DIM*HID+(long)HID*OUT_DIM)/256),256,0,stream>>>(W1, W2, wt1, wt2, modep);

  // layer 1 (gemm + fused dots1)
  gemm_k<<<dim3(HID/64,(N_NODES+63)/64),256,0,stream>>>(
      h_in, wt1, f1b, N_NODES, HID, IN_DIM, 1, modep, al1, ar1, el1, er1, 1);
  agg1_k<<<N_NODES,256,0,stream>>>(f1b, el1, er1, cnt, bucket, xbuf);

  // layer 2 (gemm + fused dots2)
  gemm_k<<<dim3(OUT_DIM/64,(N_NODES+63)/64),256,0,stream>>>(
      xbuf, wt2, f2b, N_NODES, OUT_DIM, HID, 0, modep, al2, ar2, el2, er2, 2);
  agg2_k<<<N_NODES,128,0,stream>>>(f2b, el2, er2, cnt, bucket, d_out, modep);
}

// Round 6
// 193.996 us; speedup vs baseline: 2.3973x; 1.0269x over previous
//
#include <hip/hip_runtime.h>
#include <hip/hip_bf16.h>

#define N_NODES 10000
#define IN_DIM 256
#define HID 512      // HEADS*HIDDEN
#define HEADS 8
#define OUT_DIM 256
#define NEG 0.2f
#define CAP 128      // bucket capacity per node (actual max deg ~57 incl self-loop)

typedef __hip_bfloat16 bf16;
typedef __attribute__((ext_vector_type(8))) short short8;
typedef __attribute__((ext_vector_type(4))) float f32x4;

__device__ __forceinline__ float ldm(const void* p, long i, int mode){
  if(mode) return ((const float*)p)[i];
  return __bfloat162float(((const bf16*)p)[i]);
}
__device__ __forceinline__ unsigned short f2bf(float f){
  bf16 b = __float2bfloat16(f);
  return *(unsigned short*)&b;
}
__device__ __forceinline__ float bflo(unsigned int u){ return __uint_as_float(u<<16); }
__device__ __forceinline__ float bfhi(unsigned int u){ return __uint_as_float(u&0xffff0000u); }

// block 0: sniff bf16-vs-f32. blocks 1..: zero cnt + el/er accumulators.
__global__ void detect_zero_k(const unsigned short* w1raw, int* mode, int* cnt,
                              float* el1, float* er1, float* el2, float* er2){
  int t = threadIdx.x;
  if(blockIdx.x==0){
    __shared__ int sbad;
    if(t==0) sbad=0;
    __syncthreads();
    int bad=0;
    for(int i=t;i<512;i+=256){
      unsigned int u = ((unsigned int)w1raw[i])<<16;
      float f = __uint_as_float(u);
      if(!(f==f) || fabsf(f) > 100.0f) bad++;
    }
    #pragma unroll
    for(int o=32;o>0;o>>=1) bad += __shfl_down(bad,o);
    if((t&63)==0) atomicAdd(&sbad, bad);
    __syncthreads();
    if(t==0) *mode = (sbad>10) ? 1 : 0;
  } else {
    int i = (blockIdx.x-1)*256 + t;   // covers [0, 80000)
    if(i<N_NODES*HEADS){ el1[i]=0.f; er1[i]=0.f; }
    if(i<N_NODES){ cnt[i]=0; el2[i]=0.f; er2[i]=0.f; }
  }
}

// bucketed CSR build: one pass, no hist/scan.
__global__ void scatter_k(const int* src, const int* dst, int* cnt, int* bucket, int E){
  int e = blockIdx.x*256 + threadIdx.x;
  if(e<E){
    int d = dst[e];
    int pos = atomicAdd(&cnt[d], 1);
    if(pos < CAP) bucket[(long)d*CAP + pos] = src[e];
  }
}

// Both weight transposes: W1[K1][HID]->wt1[HID][K1], W2[K2][OUT]->wt2[OUT][K2].
__global__ void wprep_k(const void* W1, const void* W2, unsigned short* wt1,
                        unsigned short* wt2, const int* modep){
  int md = *modep;
  long i = (long)blockIdx.x*256 + threadIdx.x;
  const long n1 = (long)IN_DIM*HID;
  if(i < n1){
    int k = (int)(i/HID), n = (int)(i%HID);
    unsigned short v = md ? f2bf(((const float*)W1)[i]) : ((const unsigned short*)W1)[i];
    wt1[(long)n*IN_DIM + k] = v;
  } else {
    long j = i - n1;
    int k = (int)(j/OUT_DIM), n = (int)(j%OUT_DIM);
    unsigned short v = md ? f2bf(((const float*)W2)[j]) : ((const unsigned short*)W2)[j];
    wt2[(long)n*HID + k] = v;
  }
}

// C[M,N]bf16 = A[M,K] @ Bt[N,K]^T with fused attention-dot epilogue.
// 64x64 tile, BK=32, 4 waves (each 32x32 = 2x2 16x16x32 frags).
// dmode==1: el stride 8, head = nbase>>6 (layer1). dmode==2: el stride 1 (layer2).
__global__ __launch_bounds__(256) void gemm_k(const void* A, const unsigned short* Bt,
                                              unsigned short* C, int M, int N, int K,
                                              int asel, const int* modep,
                                              const void* al, const void* ar,
                                              float* el, float* er, int dmode){
  int md = *modep;
  int am = asel ? md : 0;   // 1 -> A is f32
  __shared__ short As[64*40];
  __shared__ short Bs[64*40];
  __shared__ float led[64], ler[64];
  int t = threadIdx.x;
  int lane = t & 63, wave = t >> 6;
  int l15 = lane & 15, quad = lane >> 4;
  int wm = (wave>>1)*32, wn = (wave&1)*32;
  int mbase = blockIdx.y*64, nbase = blockIdx.x*64;

  f32x4 acc[2][2];
  #pragma unroll
  for(int i=0;i<2;i++)
    #pragma unroll
    for(int j=0;j<2;j++) acc[i][j] = (f32x4){0.f,0.f,0.f,0.f};

  int row = t>>2, kk = (t&3)*8;
  long arow = (long)(mbase+row)*K, brow = (long)(nbase+row)*K;
  bool av = (mbase+row) < M;
  const unsigned short* Ab = (const unsigned short*)A;
  const float* Af = (const float*)A;

  for(int k0=0;k0<K;k0+=32){
    short8 a = (short8){0,0,0,0,0,0,0,0};
    if(am){
      if(av){
        float4 x = *(const float4*)(Af + arow + k0 + kk);
        float4 y = *(const float4*)(Af + arow + k0 + kk + 4);
        a[0]=f2bf(x.x); a[1]=f2bf(x.y); a[2]=f2bf(x.z); a[3]=f2bf(x.w);
        a[4]=f2bf(y.x); a[5]=f2bf(y.y); a[6]=f2bf(y.z); a[7]=f2bf(y.w);
      }
    } else {
      if(av) a = *(const short8*)(Ab + arow + k0 + kk);
    }
    short8 b = *(const short8*)(Bt + brow + k0 + kk);
    __syncthreads();
    *(short8*)(As + row*40 + kk) = a;
    *(short8*)(Bs + row*40 + kk) = b;
    __syncthreads();
    short8 af[2], bfr[2];
    #pragma unroll
    for(int mi=0;mi<2;mi++) af[mi]  = *(short8*)(As + (wm + mi*16 + l15)*40 + quad*8);
    #pragma unroll
    for(int ni=0;ni<2;ni++) bfr[ni] = *(short8*)(Bs + (wn + ni*16 + l15)*40 + quad*8);
    #pragma unroll
    for(int mi=0;mi<2;mi++)
      #pragma unroll
      for(int ni=0;ni<2;ni++)
        acc[mi][ni] = __builtin_amdgcn_mfma_f32_16x16x32_bf16(af[mi], bfr[ni], acc[mi][ni], 0,0,0);
  }

  // C store (bf16)
  #pragma unroll
  for(int mi=0;mi<2;mi++){
    #pragma unroll
    for(int ni=0;ni<2;ni++){
      int grow0 = mbase + wm + mi*16 + quad*4;
      int gcol  = nbase + wn + ni*16 + l15;
      #pragma unroll
      for(int r=0;r<4;r++){
        int grow = grow0 + r;
        if(grow < M) C[(long)grow*N + gcol] = f2bf(acc[mi][ni][r]);
      }
    }
  }

  // fused dots epilogue: partial el/er for this block's 64 rows
  float avv[2], rvv[2];
  #pragma unroll
  for(int ni=0;ni<2;ni++){
    int gc = nbase + wn + ni*16 + l15;
    avv[ni] = ldm(al, gc, md);
    rvv[ni] = ldm(ar, gc, md);
  }
  __syncthreads();
  if(t<64){ led[t]=0.f; ler[t]=0.f; }
  __syncthreads();
  #pragma unroll
  for(int mi=0;mi<2;mi++){
    #pragma unroll
    for(int r=0;r<4;r++){
      float pl = acc[mi][0][r]*avv[0] + acc[mi][1][r]*avv[1];
      float pr = acc[mi][0][r]*rvv[0] + acc[mi][1][r]*rvv[1];
      #pragma unroll
      for(int o=1;o<16;o<<=1){ pl += __shfl_xor(pl,o); pr += __shfl_xor(pr,o); }
      if(l15==0){
        int lr = wm + mi*16 + quad*4 + r;
        atomicAdd(&led[lr], pl);
        atomicAdd(&ler[lr], pr);
      }
    }
  }
  __syncthreads();
  if(t<64){
    int grow = mbase + t;
    if(grow < M){
      int estride = (dmode==1) ? HEADS : 1;
      int hidx    = (dmode==1) ? (nbase>>6) : 0;
      atomicAdd(&el[(long)grow*estride + hidx], led[t]);
      atomicAdd(&er[(long)grow*estride + hidx], ler[t]);
    }
  }
}

// Layer-1 edge softmax + aggregate + ELU -> bf16 x. One block(128) per dst node.
// Thread t owns cols 4t..4t+3 (uint2 = 4 bf16), head = t>>4.
__global__ __launch_bounds__(128) void agg1_k(const unsigned short* fb, const float* el,
                       const float* er, const int* cnt, const int* bucket, unsigned short* x){
  int n = blockIdx.x, t = threadIdx.x;
  long off = (long)n*CAP;
  int deg = cnt[n]; if(deg>CAP) deg=CAP;
  __shared__ float wsum[8], ers[8];
  __shared__ int sidx[CAP];
  __shared__ float wlds[CAP*8];
  if(t<8){ wsum[t]=0.f; ers[t]=er[n*HEADS+t]; }
  for(int i=t;i<deg;i+=128) sidx[i]=bucket[off+i];
  __syncthreads();
  {
    int tot = deg*HEADS;
    float pw = 0.f;
    int myh = t&7;                       // stride 128 preserves head
    float erh = ers[myh];
    for(int p=t; p<tot; p+=128){
      int i = p>>3;
      int s = sidx[i];
      float e = el[s*HEADS+myh] + erh;
      e = e>0.f ? e : NEG*e;
      float w = __expf(e);
      wlds[p]=w;
      pw += w;
    }
    #pragma unroll
    for(int o=32;o>=8;o>>=1) pw += __shfl_xor(pw,o);
    if((t&63)<8) atomicAdd(&wsum[t&63], pw);
  }
  __syncthreads();
  if(t<8) wsum[t] = wsum[t]>0.f ? 1.f/wsum[t] : 0.f;
  __syncthreads();
  int c0 = 4*t;
  int h = t>>4;
  float inv = wsum[h];
  float a0=0.f,a1=0.f,a2=0.f,a3=0.f;
  #pragma unroll 4
  for(int i=0;i<deg;i++){
    int s = sidx[i];
    float w = wlds[i*8+h];
    uint2 u = *(const uint2*)(fb + (long)s*HID + c0);
    a0 += w*bflo(u.x); a1 += w*bfhi(u.x);
    a2 += w*bflo(u.y); a3 += w*bfhi(u.y);
  }
  a0*=inv; a1*=inv; a2*=inv; a3*=inv;
  a0 = a0>0.f ? a0 : __expf(a0)-1.f;   // ELU
  a1 = a1>0.f ? a1 : __expf(a1)-1.f;
  a2 = a2>0.f ? a2 : __expf(a2)-1.f;
  a3 = a3>0.f ? a3 : __expf(a3)-1.f;
  uint2 o2;
  o2.x = (unsigned int)f2bf(a0) | ((unsigned int)f2bf(a1)<<16);
  o2.y = (unsigned int)f2bf(a2) | ((unsigned int)f2bf(a3)<<16);
  *(uint2*)(x + (long)n*HID + c0) = o2;
}

// Layer-2 edge softmax + aggregate -> final output. One block(64) per dst node.
// Thread t owns cols 4t..4t+3.
__global__ __launch_bounds__(64) void agg2_k(const unsigned short* fb, const float* el,
                       const float* er, const int* cnt, const int* bucket, void* out,
                       const int* modep){
  int md = *modep;
  int n = blockIdx.x, t = threadIdx.x;
  long off = (long)n*CAP;
  int deg = cnt[n]; if(deg>CAP) deg=CAP;
  __shared__ int sidx[CAP];
  __shared__ float wlds[CAP];
  for(int i=t;i<deg;i+=64) sidx[i]=bucket[off+i];
  __syncthreads();
  float ern = er[n];
  float pw = 0.f;
  for(int i=t; i<deg; i+=64){
    int s = sidx[i];
    float e = el[s]+ern; e = e>0.f ? e : NEG*e;
    float w = __expf(e);
    wlds[i]=w;
    pw += w;
  }
  #pragma unroll
  for(int o=32;o>0;o>>=1) pw += __shfl_xor(pw,o);   // all lanes hold sum
  float inv = pw>0.f ? 1.f/pw : 0.f;
  __syncthreads();
  int c0 = 4*t;
  float a0=0.f,a1=0.f,a2=0.f,a3=0.f;
  #pragma unroll 4
  for(int i=0;i<deg;i++){
    int s = sidx[i];
    float w = wlds[i];
    uint2 u = *(const uint2*)(fb + (long)s*OUT_DIM + c0);
    a0 += w*bflo(u.x); a1 += w*bfhi(u.x);
    a2 += w*bflo(u.y); a3 += w*bfhi(u.y);
  }
  a0*=inv; a1*=inv; a2*=inv; a3*=inv;
  long oi = (long)n*OUT_DIM + c0;
  if(md){
    float4 fo; fo.x=a0; fo.y=a1; fo.z=a2; fo.w=a3;
    *(float4*)((float*)out + oi) = fo;
  } else {
    uint2 o2;
    o2.x = (unsigned int)f2bf(a0) | ((unsigned int)f2bf(a1)<<16);
    o2.y = (unsigned int)f2bf(a2) | ((unsigned int)f2bf(a3)<<16);
    *(uint2*)((unsigned short*)out + oi) = o2;
  }
}

extern "C" void kernel_launch(void* const* d_in, const int* in_sizes, int n_in,
                              void* d_out, int out_size, void* d_ws, size_t ws_size,
                              hipStream_t stream){
  (void)n_in; (void)out_size; (void)ws_size;
  const void* h_in = d_in[0];
  const void* W1   = d_in[1];
  const void* al1  = d_in[2];
  const void* ar1  = d_in[3];
  const void* W2   = d_in[4];
  const void* al2  = d_in[5];
  const void* ar2  = d_in[6];
  const int* src = (const int*)d_in[7];
  const int* dst = (const int*)d_in[8];
  int E = in_sizes[7];

  char* ws = (char*)d_ws;
  size_t o = 0;
  auto alloc = [&](size_t b){ size_t c=o; o += (b+255)&~(size_t)255; return c; };
  unsigned short* f1b  = (unsigned short*)(ws + alloc((size_t)N_NODES*HID*2));
  unsigned short* f2b  = (unsigned short*)(ws + alloc((size_t)N_NODES*OUT_DIM*2));
  unsigned short* xbuf = (unsigned short*)(ws + alloc((size_t)N_NODES*HID*2));
  unsigned short* wt1  = (unsigned short*)(ws + alloc((size_t)IN_DIM*HID*2));
  unsigned short* wt2  = (unsigned short*)(ws + alloc((size_t)HID*OUT_DIM*2));
  float* el1   = (float*)(ws + alloc((size_t)N_NODES*HEADS*4));
  float* er1   = (float*)(ws + alloc((size_t)N_NODES*HEADS*4));
  float* el2   = (float*)(ws + alloc((size_t)N_NODES*4));
  float* er2   = (float*)(ws + alloc((size_t)N_NODES*4));
  int* cnt     = (int*)(ws + alloc((size_t)N_NODES*4));
  int* bucket  = (int*)(ws + alloc((size_t)N_NODES*CAP*4));
  int* modep   = (int*)(ws + alloc(256));

  detect_zero_k<<<1+(N_NODES*HEADS+255)/256,256,0,stream>>>(
      (const unsigned short*)W1, modep, cnt, el1, er1, el2, er2);
  scatter_k<<<(E+255)/256,256,0,stream>>>(src, dst, cnt, bucket, E);
  wprep_k<<<(int)(((long)IN_DIM*HID+(long)HID*OUT_DIM)/256),256,0,stream>>>(W1, W2, wt1, wt2, modep);

  // layer 1 (gemm + fused dots1)
  gemm_k<<<dim3(HID/64,(N_NODES+63)/64),256,0,stream>>>(
      h_in, wt1, f1b, N_NODES, HID, IN_DIM, 1, modep, al1, ar1, el1, er1, 1);
  agg1_k<<<N_NODES,128,0,stream>>>(f1b, el1, er1, cnt, bucket, xbuf);

  // layer 2 (gemm + fused dots2)
  gemm_k<<<dim3(OUT_DIM/64,(N_NODES+63)/64),256,0,stream>>>(
      xbuf, wt2, f2b, N_NODES, OUT_DIM, HID, 0, modep, al2, ar2, el2, er2, 2);
  agg2_k<<<N_NODES,64,0,stream>>>(f2b, el2, er2, cnt, bucket, d_out, modep);
}

// Round 7
// 189.553 us; speedup vs baseline: 2.4535x; 1.0234x over previous
//
#include <hip/hip_runtime.h>
#include <hip/hip_bf16.h>

#define N_NODES 10000
#define IN_DIM 256
#define HID 512      // HEADS*HIDDEN
#define HEADS 8
#define OUT_DIM 256
#define NEG 0.2f
#define CAP 128      // bucket capacity per node (actual max deg ~57 incl self-loop)
#define WPREP_BLOCKS (((IN_DIM*HID)+(HID*OUT_DIM))/256)   // 1024

typedef __hip_bfloat16 bf16;
typedef __attribute__((ext_vector_type(8))) short short8;
typedef __attribute__((ext_vector_type(4))) float f32x4;

__device__ __forceinline__ float ldm(const void* p, long i, int mode){
  if(mode) return ((const float*)p)[i];
  return __bfloat162float(((const bf16*)p)[i]);
}
__device__ __forceinline__ unsigned short f2bf(float f){
  bf16 b = __float2bfloat16(f);
  return *(unsigned short*)&b;
}
__device__ __forceinline__ float bflo(unsigned int u){ return __uint_as_float(u<<16); }
__device__ __forceinline__ float bfhi(unsigned int u){ return __uint_as_float(u&0xffff0000u); }

// block 0: sniff bf16-vs-f32. blocks 1..: zero cnt + el/er accumulators.
__global__ void detect_zero_k(const unsigned short* w1raw, int* mode, int* cnt,
                              float* el1, float* er1, float* el2, float* er2){
  int t = threadIdx.x;
  if(blockIdx.x==0){
    __shared__ int sbad;
    if(t==0) sbad=0;
    __syncthreads();
    int bad=0;
    for(int i=t;i<512;i+=256){
      unsigned int u = ((unsigned int)w1raw[i])<<16;
      float f = __uint_as_float(u);
      if(!(f==f) || fabsf(f) > 100.0f) bad++;
    }
    #pragma unroll
    for(int o=32;o>0;o>>=1) bad += __shfl_down(bad,o);
    if((t&63)==0) atomicAdd(&sbad, bad);
    __syncthreads();
    if(t==0) *mode = (sbad>10) ? 1 : 0;
  } else {
    int i = (blockIdx.x-1)*256 + t;   // covers [0, 80000)
    if(i<N_NODES*HEADS){ el1[i]=0.f; er1[i]=0.f; }
    if(i<N_NODES){ cnt[i]=0; el2[i]=0.f; er2[i]=0.f; }
  }
}

// blocks [0,WPREP_BLOCKS): weight transpose W1->wt1[HID][K1], W2->wt2[OUT][K2].
// blocks [WPREP_BLOCKS,..): bucketed CSR scatter (cnt pre-zeroed by detect_zero_k).
__global__ void prep2_k(const void* W1, const void* W2, unsigned short* wt1,
                        unsigned short* wt2, const int* modep,
                        const int* src, const int* dst, int* cnt, int* bucket, int E){
  int b = blockIdx.x, t = threadIdx.x;
  if(b < WPREP_BLOCKS){
    int md = *modep;
    long i = (long)b*256 + t;
    const long n1 = (long)IN_DIM*HID;
    if(i < n1){
      int k = (int)(i/HID), n = (int)(i%HID);
      unsigned short v = md ? f2bf(((const float*)W1)[i]) : ((const unsigned short*)W1)[i];
      wt1[(long)n*IN_DIM + k] = v;
    } else {
      long j = i - n1;
      int k = (int)(j/OUT_DIM), n = (int)(j%OUT_DIM);
      unsigned short v = md ? f2bf(((const float*)W2)[j]) : ((const unsigned short*)W2)[j];
      wt2[(long)n*HID + k] = v;
    }
  } else {
    int e = (b-WPREP_BLOCKS)*256 + t;
    if(e<E){
      int d = dst[e];
      int pos = atomicAdd(&cnt[d], 1);
      if(pos < CAP) bucket[(long)d*CAP + pos] = src[e];
    }
  }
}

// C[M,N]bf16 = A[M,K] @ Bt[N,K]^T with fused attention-dot epilogue.
// 64x64 tile, BK=32, 4 waves (each 32x32 = 2x2 16x16x32 frags).
// dmode==1: el stride 8, head = nbase>>6 (layer1). dmode==2: el stride 1 (layer2).
__global__ __launch_bounds__(256) void gemm_k(const void* A, const unsigned short* Bt,
                                              unsigned short* C, int M, int N, int K,
                                              int asel, const int* modep,
                                              const void* al, const void* ar,
                                              float* el, float* er, int dmode){
  int md = *modep;
  int am = asel ? md : 0;   // 1 -> A is f32
  __shared__ short As[64*40];
  __shared__ short Bs[64*40];
  __shared__ float led[64], ler[64];
  int t = threadIdx.x;
  int lane = t & 63, wave = t >> 6;
  int l15 = lane & 15, quad = lane >> 4;
  int wm = (wave>>1)*32, wn = (wave&1)*32;
  int mbase = blockIdx.y*64, nbase = blockIdx.x*64;

  f32x4 acc[2][2];
  #pragma unroll
  for(int i=0;i<2;i++)
    #pragma unroll
    for(int j=0;j<2;j++) acc[i][j] = (f32x4){0.f,0.f,0.f,0.f};

  int row = t>>2, kk = (t&3)*8;
  long arow = (long)(mbase+row)*K, brow = (long)(nbase+row)*K;
  bool av = (mbase+row) < M;
  const unsigned short* Ab = (const unsigned short*)A;
  const float* Af = (const float*)A;

  for(int k0=0;k0<K;k0+=32){
    short8 a = (short8){0,0,0,0,0,0,0,0};
    if(am){
      if(av){
        float4 x = *(const float4*)(Af + arow + k0 + kk);
        float4 y = *(const float4*)(Af + arow + k0 + kk + 4);
        a[0]=f2bf(x.x); a[1]=f2bf(x.y); a[2]=f2bf(x.z); a[3]=f2bf(x.w);
        a[4]=f2bf(y.x); a[5]=f2bf(y.y); a[6]=f2bf(y.z); a[7]=f2bf(y.w);
      }
    } else {
      if(av) a = *(const short8*)(Ab + arow + k0 + kk);
    }
    short8 b = *(const short8*)(Bt + brow + k0 + kk);
    __syncthreads();
    *(short8*)(As + row*40 + kk) = a;
    *(short8*)(Bs + row*40 + kk) = b;
    __syncthreads();
    short8 af[2], bfr[2];
    #pragma unroll
    for(int mi=0;mi<2;mi++) af[mi]  = *(short8*)(As + (wm + mi*16 + l15)*40 + quad*8);
    #pragma unroll
    for(int ni=0;ni<2;ni++) bfr[ni] = *(short8*)(Bs + (wn + ni*16 + l15)*40 + quad*8);
    #pragma unroll
    for(int mi=0;mi<2;mi++)
      #pragma unroll
      for(int ni=0;ni<2;ni++)
        acc[mi][ni] = __builtin_amdgcn_mfma_f32_16x16x32_bf16(af[mi], bfr[ni], acc[mi][ni], 0,0,0);
  }

  // C store (bf16)
  #pragma unroll
  for(int mi=0;mi<2;mi++){
    #pragma unroll
    for(int ni=0;ni<2;ni++){
      int grow0 = mbase + wm + mi*16 + quad*4;
      int gcol  = nbase + wn + ni*16 + l15;
      #pragma unroll
      for(int r=0;r<4;r++){
        int grow = grow0 + r;
        if(grow < M) C[(long)grow*N + gcol] = f2bf(acc[mi][ni][r]);
      }
    }
  }

  // fused dots epilogue: partial el/er for this block's 64 rows
  float avv[2], rvv[2];
  #pragma unroll
  for(int ni=0;ni<2;ni++){
    int gc = nbase + wn + ni*16 + l15;
    avv[ni] = ldm(al, gc, md);
    rvv[ni] = ldm(ar, gc, md);
  }
  __syncthreads();
  if(t<64){ led[t]=0.f; ler[t]=0.f; }
  __syncthreads();
  #pragma unroll
  for(int mi=0;mi<2;mi++){
    #pragma unroll
    for(int r=0;r<4;r++){
      float pl = acc[mi][0][r]*avv[0] + acc[mi][1][r]*avv[1];
      float pr = acc[mi][0][r]*rvv[0] + acc[mi][1][r]*rvv[1];
      #pragma unroll
      for(int o=1;o<16;o<<=1){ pl += __shfl_xor(pl,o); pr += __shfl_xor(pr,o); }
      if(l15==0){
        int lr = wm + mi*16 + quad*4 + r;
        atomicAdd(&led[lr], pl);
        atomicAdd(&ler[lr], pr);
      }
    }
  }
  __syncthreads();
  if(t<64){
    int grow = mbase + t;
    if(grow < M){
      int estride = (dmode==1) ? HEADS : 1;
      int hidx    = (dmode==1) ? (nbase>>6) : 0;
      atomicAdd(&el[(long)grow*estride + hidx], led[t]);
      atomicAdd(&er[(long)grow*estride + hidx], ler[t]);
    }
  }
}

// Layer-1 agg, column-sliced: grid = 4*N_NODES (head-pair hp = b/N, slowest-varying
// so co-resident blocks share a 2.5 MB L2-resident feat slice). 1 wave per block.
// Thread t owns cols hp*128 + 2t, 2t+1 (head h0 for t<32, h1 for t>=32).
__global__ __launch_bounds__(64) void agg1_k(const unsigned short* fb, const float* el,
                       const float* er, const int* cnt, const int* bucket, unsigned short* x){
  int b = blockIdx.x;
  int hp = b / N_NODES;
  int n  = b - hp*N_NODES;
  int t = threadIdx.x;
  long off = (long)n*CAP;
  int deg = cnt[n]; if(deg>CAP) deg=CAP;
  __shared__ int sidx[CAP];
  __shared__ float w0[CAP], w1[CAP];
  for(int i=t;i<deg;i+=64) sidx[i]=bucket[off+i];
  __syncthreads();
  int h0 = 2*hp;
  float er0 = er[n*HEADS+h0], er1 = er[n*HEADS+h0+1];
  float pw0=0.f, pw1=0.f;
  for(int i=t;i<deg;i+=64){
    int s = sidx[i];
    float2 ev = *(const float2*)(el + (long)s*HEADS + h0);   // h0 even -> 8B aligned
    float e0 = ev.x + er0; e0 = e0>0.f?e0:NEG*e0;
    float e1 = ev.y + er1; e1 = e1>0.f?e1:NEG*e1;
    float wa = __expf(e0), wb = __expf(e1);
    w0[i]=wa; w1[i]=wb;
    pw0+=wa; pw1+=wb;
  }
  #pragma unroll
  for(int o=32;o>0;o>>=1){ pw0 += __shfl_xor(pw0,o); pw1 += __shfl_xor(pw1,o); }
  float inv0 = pw0>0.f?1.f/pw0:0.f, inv1 = pw1>0.f?1.f/pw1:0.f;
  __syncthreads();
  int c0 = hp*128 + 2*t;
  const float* wsel = (t<32)? w0 : w1;
  float inv = (t<32)? inv0 : inv1;
  float a0=0.f, a1=0.f;
  #pragma unroll 4
  for(int i=0;i<deg;i++){
    int s = sidx[i];
    float w = wsel[i];
    unsigned int u = *(const unsigned int*)(fb + (long)s*HID + c0);
    a0 += w*bflo(u); a1 += w*bfhi(u);
  }
  a0*=inv; a1*=inv;
  a0 = a0>0.f ? a0 : __expf(a0)-1.f;   // ELU
  a1 = a1>0.f ? a1 : __expf(a1)-1.f;
  *(unsigned int*)(x + (long)n*HID + c0) =
      (unsigned int)f2bf(a0) | ((unsigned int)f2bf(a1)<<16);
}

// Layer-2 agg, column-sliced: grid = 2*N_NODES (half ch = b/N slowest). 1 wave.
// Thread t owns cols ch*128 + 2t, 2t+1.
__global__ __launch_bounds__(64) void agg2_k(const unsigned short* fb, const float* el,
                       const float* er, const int* cnt, const int* bucket, void* out,
                       const int* modep){
  int md = *modep;
  int b = blockIdx.x;
  int ch = b / N_NODES;
  int n  = b - ch*N_NODES;
  int t = threadIdx.x;
  long off = (long)n*CAP;
  int deg = cnt[n]; if(deg>CAP) deg=CAP;
  __shared__ int sidx[CAP];
  __shared__ float wl[CAP];
  for(int i=t;i<deg;i+=64) sidx[i]=bucket[off+i];
  __syncthreads();
  float ern = er[n];
  float pw = 0.f;
  for(int i=t;i<deg;i+=64){
    int s = sidx[i];
    float e = el[s]+ern; e = e>0.f ? e : NEG*e;
    float w = __expf(e);
    wl[i]=w;
    pw += w;
  }
  #pragma unroll
  for(int o=32;o>0;o>>=1) pw += __shfl_xor(pw,o);
  float inv = pw>0.f ? 1.f/pw : 0.f;
  __syncthreads();
  int c0 = ch*128 + 2*t;
  float a0=0.f, a1=0.f;
  #pragma unroll 4
  for(int i=0;i<deg;i++){
    int s = sidx[i];
    float w = wl[i];
    unsigned int u = *(const unsigned int*)(fb + (long)s*OUT_DIM + c0);
    a0 += w*bflo(u); a1 += w*bfhi(u);
  }
  a0*=inv; a1*=inv;
  long oi = (long)n*OUT_DIM + c0;
  if(md){
    float2 fo; fo.x=a0; fo.y=a1;
    *(float2*)((float*)out + oi) = fo;
  } else {
    *(unsigned int*)((unsigned short*)out + oi) =
        (unsigned int)f2bf(a0) | ((unsigned int)f2bf(a1)<<16);
  }
}

extern "C" void kernel_launch(void* const* d_in, const int* in_sizes, int n_in,
                              void* d_out, int out_size, void* d_ws, size_t ws_size,
                              hipStream_t stream){
  (void)n_in; (void)out_size; (void)ws_size;
  const void* h_in = d_in[0];
  const void* W1   = d_in[1];
  const void* al1  = d_in[2];
  const void* ar1  = d_in[3];
  const void* W2   = d_in[4];
  const void* al2  = d_in[5];
  const void* ar2  = d_in[6];
  const int* src = (const int*)d_in[7];
  const int* dst = (const int*)d_in[8];
  int E = in_sizes[7];

  char* ws = (char*)d_ws;
  size_t o = 0;
  auto alloc = [&](size_t b){ size_t c=o; o += (b+255)&~(size_t)255; return c; };
  unsigned short* f1b  = (unsigned short*)(ws + alloc((size_t)N_NODES*HID*2));
  unsigned short* f2b  = (unsigned short*)(ws + alloc((size_t)N_NODES*OUT_DIM*2));
  unsigned short* xbuf = (unsigned short*)(ws + alloc((size_t)N_NODES*HID*2));
  unsigned short* wt1  = (unsigned short*)(ws + alloc((size_t)IN_DIM*HID*2));
  unsigned short* wt2  = (unsigned short*)(ws + alloc((size_t)HID*OUT_DIM*2));
  float* el1   = (float*)(ws + alloc((size_t)N_NODES*HEADS*4));
  float* er1   = (float*)(ws + alloc((size_t)N_NODES*HEADS*4));
  float* el2   = (float*)(ws + alloc((size_t)N_NODES*4));
  float* er2   = (float*)(ws + alloc((size_t)N_NODES*4));
  int* cnt     = (int*)(ws + alloc((size_t)N_NODES*4));
  int* bucket  = (int*)(ws + alloc((size_t)N_NODES*CAP*4));
  int* modep   = (int*)(ws + alloc(256));

  detect_zero_k<<<1+(N_NODES*HEADS+255)/256,256,0,stream>>>(
      (const unsigned short*)W1, modep, cnt, el1, er1, el2, er2);
  prep2_k<<<WPREP_BLOCKS+(E+255)/256,256,0,stream>>>(
      W1, W2, wt1, wt2, modep, src, dst, cnt, bucket, E);

  // layer 1 (gemm + fused dots1)
  gemm_k<<<dim3(HID/64,(N_NODES+63)/64),256,0,stream>>>(
      h_in, wt1, f1b, N_NODES, HID, IN_DIM, 1, modep, al1, ar1, el1, er1, 1);
  agg1_k<<<4*N_NODES,64,0,stream>>>(f1b, el1, er1, cnt, bucket, xbuf);

  // layer 2 (gemm + fused dots2)
  gemm_k<<<dim3(OUT_DIM/64,(N_NODES+63)/64),256,0,stream>>>(
      xbuf, wt2, f2b, N_NODES, OUT_DIM, HID, 0, modep, al2, ar2, el2, er2, 2);
  agg2_k<<<2*N_NODES,64,0,stream>>>(f2b, el2, er2, cnt, bucket, d_out, modep);
}

// Round 9
// 184.132 us; speedup vs baseline: 2.5258x; 1.0294x over previous
//
#include <hip/hip_runtime.h>
#include <hip/hip_bf16.h>

#define N_NODES 10000
#define IN_DIM 256
#define HID 512      // HEADS*HIDDEN
#define HEADS 8
#define OUT_DIM 256
#define NEG 0.2f
#define CAP 128      // bucket capacity per node (actual max deg ~57 incl self-loop)
#define WPREP_BLOCKS (((IN_DIM*HID)+(HID*OUT_DIM))/256)   // 1024

typedef __hip_bfloat16 bf16;
typedef __attribute__((ext_vector_type(8))) short short8;
typedef __attribute__((ext_vector_type(4))) float f32x4;

__device__ __forceinline__ float ldm(const void* p, long i, int mode){
  if(mode) return ((const float*)p)[i];
  return __bfloat162float(((const bf16*)p)[i]);
}
__device__ __forceinline__ unsigned short f2bf(float f){
  bf16 b = __float2bfloat16(f);
  return *(unsigned short*)&b;
}
__device__ __forceinline__ float bflo(unsigned int u){ return __uint_as_float(u<<16); }
__device__ __forceinline__ float bfhi(unsigned int u){ return __uint_as_float(u&0xffff0000u); }

// block 0: sniff bf16-vs-f32. blocks 1..: zero cnt + el2/er2 (el1/er1 are
// direct-stored by gemm1's epilogue — no zeroing needed).
__global__ void detect_zero_k(const unsigned short* w1raw, int* mode, int* cnt,
                              float* el2, float* er2){
  int t = threadIdx.x;
  if(blockIdx.x==0){
    __shared__ int sbad;
    if(t==0) sbad=0;
    __syncthreads();
    int bad=0;
    for(int i=t;i<512;i+=256){
      unsigned int u = ((unsigned int)w1raw[i])<<16;
      float f = __uint_as_float(u);
      if(!(f==f) || fabsf(f) > 100.0f) bad++;
    }
    #pragma unroll
    for(int o=32;o>0;o>>=1) bad += __shfl_down(bad,o);
    if((t&63)==0) atomicAdd(&sbad, bad);
    __syncthreads();
    if(t==0) *mode = (sbad>10) ? 1 : 0;
  } else {
    int i = (blockIdx.x-1)*256 + t;
    if(i<N_NODES){ cnt[i]=0; el2[i]=0.f; er2[i]=0.f; }
  }
}

// blocks [0,WPREP_BLOCKS): weight transpose W1->wt1[HID][K1], W2->wt2[OUT][K2].
// blocks [WPREP_BLOCKS,..): bucketed CSR scatter (cnt pre-zeroed).
__global__ void prep2_k(const void* W1, const void* W2, unsigned short* wt1,
                        unsigned short* wt2, const int* modep,
                        const int* src, const int* dst, int* cnt, int* bucket, int E){
  int b = blockIdx.x, t = threadIdx.x;
  if(b < WPREP_BLOCKS){
    int md = *modep;
    long i = (long)b*256 + t;
    const long n1 = (long)IN_DIM*HID;
    if(i < n1){
      int k = (int)(i/HID), n = (int)(i%HID);
      unsigned short v = md ? f2bf(((const float*)W1)[i]) : ((const unsigned short*)W1)[i];
      wt1[(long)n*IN_DIM + k] = v;
    } else {
      long j = i - n1;
      int k = (int)(j/OUT_DIM), n = (int)(j%OUT_DIM);
      unsigned short v = md ? f2bf(((const float*)W2)[j]) : ((const unsigned short*)W2)[j];
      wt2[(long)n*HID + k] = v;
    }
  } else {
    int e = (b-WPREP_BLOCKS)*256 + t;
    if(e<E){
      int d = dst[e];
      int pos = atomicAdd(&cnt[d], 1);
      if(pos < CAP) bucket[(long)d*CAP + pos] = src[e];
    }
  }
}

// C[M,N]bf16 = A[M,K] @ Bt[N,K]^T with fused attention-dot epilogue.
// 64x64 tile, BK=32, 4 waves (each 32x32 = 2x2 16x16x32 frags).
// dmode==1: el/er direct-STORE (stride 8, head=bx is sole contributor).
// dmode==2: el/er atomicAdd (stride 1, 4 col-tiles contribute).
__global__ __launch_bounds__(256) void gemm_k(const void* A, const unsigned short* Bt,
                                              unsigned short* C, int M, int N, int K,
                                              int asel, const int* modep,
                                              const void* al, const void* ar,
                                              float* el, float* er, int dmode){
  int md = *modep;
  int am = asel ? md : 0;   // 1 -> A is f32
  __shared__ short As[64*40];
  __shared__ short Bs[64*40];
  __shared__ float led[64], ler[64];
  int t = threadIdx.x;
  int lane = t & 63, wave = t >> 6;
  int l15 = lane & 15, quad = lane >> 4;
  int wm = (wave>>1)*32, wn = (wave&1)*32;
  int mbase = blockIdx.y*64, nbase = blockIdx.x*64;

  f32x4 acc[2][2];
  #pragma unroll
  for(int i=0;i<2;i++)
    #pragma unroll
    for(int j=0;j<2;j++) acc[i][j] = (f32x4){0.f,0.f,0.f,0.f};

  int row = t>>2, kk = (t&3)*8;
  long arow = (long)(mbase+row)*K, brow = (long)(nbase+row)*K;
  bool av = (mbase+row) < M;
  const unsigned short* Ab = (const unsigned short*)A;
  const float* Af = (const float*)A;

  for(int k0=0;k0<K;k0+=32){
    short8 a = (short8){0,0,0,0,0,0,0,0};
    if(am){
      if(av){
        float4 x = *(const float4*)(Af + arow + k0 + kk);
        float4 y = *(const float4*)(Af + arow + k0 + kk + 4);
        a[0]=f2bf(x.x); a[1]=f2bf(x.y); a[2]=f2bf(x.z); a[3]=f2bf(x.w);
        a[4]=f2bf(y.x); a[5]=f2bf(y.y); a[6]=f2bf(y.z); a[7]=f2bf(y.w);
      }
    } else {
      if(av) a = *(const short8*)(Ab + arow + k0 + kk);
    }
    short8 b = *(const short8*)(Bt + brow + k0 + kk);
    __syncthreads();
    *(short8*)(As + row*40 + kk) = a;
    *(short8*)(Bs + row*40 + kk) = b;
    __syncthreads();
    short8 af[2], bfr[2];
    #pragma unroll
    for(int mi=0;mi<2;mi++) af[mi]  = *(short8*)(As + (wm + mi*16 + l15)*40 + quad*8);
    #pragma unroll
    for(int ni=0;ni<2;ni++) bfr[ni] = *(short8*)(Bs + (wn + ni*16 + l15)*40 + quad*8);
    #pragma unroll
    for(int mi=0;mi<2;mi++)
      #pragma unroll
      for(int ni=0;ni<2;ni++)
        acc[mi][ni] = __builtin_amdgcn_mfma_f32_16x16x32_bf16(af[mi], bfr[ni], acc[mi][ni], 0,0,0);
  }

  // C store (bf16)
  #pragma unroll
  for(int mi=0;mi<2;mi++){
    #pragma unroll
    for(int ni=0;ni<2;ni++){
      int grow0 = mbase + wm + mi*16 + quad*4;
      int gcol  = nbase + wn + ni*16 + l15;
      #pragma unroll
      for(int r=0;r<4;r++){
        int grow = grow0 + r;
        if(grow < M) C[(long)grow*N + gcol] = f2bf(acc[mi][ni][r]);
      }
    }
  }

  // fused dots epilogue: partial el/er for this block's 64 rows
  float avv[2], rvv[2];
  #pragma unroll
  for(int ni=0;ni<2;ni++){
    int gc = nbase + wn + ni*16 + l15;
    avv[ni] = ldm(al, gc, md);
    rvv[ni] = ldm(ar, gc, md);
  }
  __syncthreads();
  if(t<64){ led[t]=0.f; ler[t]=0.f; }
  __syncthreads();
  #pragma unroll
  for(int mi=0;mi<2;mi++){
    #pragma unroll
    for(int r=0;r<4;r++){
      float pl = acc[mi][0][r]*avv[0] + acc[mi][1][r]*avv[1];
      float pr = acc[mi][0][r]*rvv[0] + acc[mi][1][r]*rvv[1];
      #pragma unroll
      for(int o=1;o<16;o<<=1){ pl += __shfl_xor(pl,o); pr += __shfl_xor(pr,o); }
      if(l15==0){
        int lr = wm + mi*16 + quad*4 + r;
        atomicAdd(&led[lr], pl);
        atomicAdd(&ler[lr], pr);
      }
    }
  }
  __syncthreads();
  if(t<64){
    int grow = mbase + t;
    if(grow < M){
      if(dmode==1){
        el[(long)grow*HEADS + blockIdx.x] = led[t];
        er[(long)grow*HEADS + blockIdx.x] = ler[t];
      } else {
        atomicAdd(&el[grow], led[t]);
        atomicAdd(&er[grow], ler[t]);
      }
    }
  }
}

// Layer-1 agg, half-sliced: grid = 2*N_NODES (half ch = b/N slowest-varying).
// 1 wave/block; thread t owns cols ch*256 + 4t..4t+3 (head ch*4 + (t>>4)).
__global__ __launch_bounds__(64) void agg1_k(const unsigned short* fb, const float* el,
                       const float* er, const int* cnt, const int* bucket, unsigned short* x){
  int b = blockIdx.x;
  int ch = b / N_NODES;
  int n  = b - ch*N_NODES;
  int t = threadIdx.x;
  long off = (long)n*CAP;
  int deg = cnt[n]; if(deg>CAP) deg=CAP;
  __shared__ int sidx[CAP];
  __shared__ float wl[4][CAP];
  for(int i=t;i<deg;i+=64) sidx[i]=bucket[off+i];
  __syncthreads();
  int h0 = ch*4;
  float4 erv = *(const float4*)(er + (long)n*HEADS + h0);   // 16B aligned
  float pw0=0.f, pw1=0.f, pw2=0.f, pw3=0.f;
  for(int i=t;i<deg;i+=64){
    int s = sidx[i];
    float4 ev = *(const float4*)(el + (long)s*HEADS + h0);
    float e0 = ev.x + erv.x; e0 = e0>0.f?e0:NEG*e0;
    float e1 = ev.y + erv.y; e1 = e1>0.f?e1:NEG*e1;
    float e2 = ev.z + erv.z; e2 = e2>0.f?e2:NEG*e2;
    float e3 = ev.w + erv.w; e3 = e3>0.f?e3:NEG*e3;
    float wa = __expf(e0), wb = __expf(e1), wc = __expf(e2), wd = __expf(e3);
    wl[0][i]=wa; wl[1][i]=wb; wl[2][i]=wc; wl[3][i]=wd;
    pw0+=wa; pw1+=wb; pw2+=wc; pw3+=wd;
  }
  #pragma unroll
  for(int o=32;o>0;o>>=1){
    pw0 += __shfl_xor(pw0,o); pw1 += __shfl_xor(pw1,o);
    pw2 += __shfl_xor(pw2,o); pw3 += __shfl_xor(pw3,o);
  }
  float invs[4];
  invs[0] = pw0>0.f?1.f/pw0:0.f; invs[1] = pw1>0.f?1.f/pw1:0.f;
  invs[2] = pw2>0.f?1.f/pw2:0.f; invs[3] = pw3>0.f?1.f/pw3:0.f;
  __syncthreads();
  int hl = t>>4;                 // local head 0..3
  int c0 = ch*256 + 4*t;
  const float* wsel = wl[hl];
  float inv = invs[hl];
  float a0=0.f,a1=0.f,a2=0.f,a3=0.f;
  #pragma unroll 4
  for(int i=0;i<deg;i++){
    int s = sidx[i];
    float w = wsel[i];
    uint2 u = *(const uint2*)(fb + (long)s*HID + c0);
    a0 += w*bflo(u.x); a1 += w*bfhi(u.x);
    a2 += w*bflo(u.y); a3 += w*bfhi(u.y);
  }
  a0*=inv; a1*=inv; a2*=inv; a3*=inv;
  a0 = a0>0.f ? a0 : __expf(a0)-1.f;   // ELU
  a1 = a1>0.f ? a1 : __expf(a1)-1.f;
  a2 = a2>0.f ? a2 : __expf(a2)-1.f;
  a3 = a3>0.f ? a3 : __expf(a3)-1.f;
  uint2 o2;
  o2.x = (unsigned int)f2bf(a0) | ((unsigned int)f2bf(a1)<<16);
  o2.y = (unsigned int)f2bf(a2) | ((unsigned int)f2bf(a3)<<16);
  *(uint2*)(x + (long)n*HID + c0) = o2;
}

// Layer-2 agg: grid = N_NODES, 1 wave; thread t owns cols 4t..4t+3 (full row).
__global__ __launch_bounds__(64) void agg2_k(const unsigned short* fb, const float* el,
                       const float* er, const int* cnt, const int* bucket, void* out,
                       const int* modep){
  int md = *modep;
  int n = blockIdx.x, t = threadIdx.x;
  long off = (long)n*CAP;
  int deg = cnt[n]; if(deg>CAP) deg=CAP;
  __shared__ int sidx[CAP];
  __shared__ float wl[CAP];
  for(int i=t;i<deg;i+=64) sidx[i]=bucket[off+i];
  __syncthreads();
  float ern = er[n];
  float pw = 0.f;
  for(int i=t;i<deg;i+=64){
    int s = sidx[i];
    float e = el[s]+ern; e = e>0.f ? e : NEG*e;
    float w = __expf(e);
    wl[i]=w;
    pw += w;
  }
  #pragma unroll
  for(int o=32;o>0;o>>=1) pw += __shfl_xor(pw,o);
  float inv = pw>0.f ? 1.f/pw : 0.f;
  __syncthreads();
  int c0 = 4*t;
  float a0=0.f,a1=0.f,a2=0.f,a3=0.f;
  #pragma unroll 4
  for(int i=0;i<deg;i++){
    int s = sidx[i];
    float w = wl[i];
    uint2 u = *(const uint2*)(fb + (long)s*OUT_DIM + c0);
    a0 += w*bflo(u.x); a1 += w*bfhi(u.x);
    a2 += w*bflo(u.y); a3 += w*bfhi(u.y);
  }
  a0*=inv; a1*=inv; a2*=inv; a3*=inv;
  long oi = (long)n*OUT_DIM + c0;
  if(md){
    float4 fo; fo.x=a0; fo.y=a1; fo.z=a2; fo.w=a3;
    *(float4*)((float*)out + oi) = fo;
  } else {
    uint2 o2;
    o2.x = (unsigned int)f2bf(a0) | ((unsigned int)f2bf(a1)<<16);
    o2.y = (unsigned int)f2bf(a2) | ((unsigned int)f2bf(a3)<<16);
    *(uint2*)((unsigned short*)out + oi) = o2;
  }
}

extern "C" void kernel_launch(void* const* d_in, const int* in_sizes, int n_in,
                              void* d_out, int out_size, void* d_ws, size_t ws_size,
                              hipStream_t stream){
  (void)n_in; (void)out_size; (void)ws_size;
  const void* h_in = d_in[0];
  const void* W1   = d_in[1];
  const void* al1  = d_in[2];
  const void* ar1  = d_in[3];
  const void* W2   = d_in[4];
  const void* al2  = d_in[5];
  const void* ar2  = d_in[6];
  const int* src = (const int*)d_in[7];
  const int* dst = (const int*)d_in[8];
  int E = in_sizes[7];

  char* ws = (char*)d_ws;
  size_t o = 0;
  auto alloc = [&](size_t b){ size_t c=o; o += (b+255)&~(size_t)255; return c; };
  unsigned short* f1b  = (unsigned short*)(ws + alloc((size_t)N_NODES*HID*2));
  unsigned short* f2b  = (unsigned short*)(ws + alloc((size_t)N_NODES*OUT_DIM*2));
  unsigned short* xbuf = (unsigned short*)(ws + alloc((size_t)N_NODES*HID*2));
  unsigned short* wt1  = (unsigned short*)(ws + alloc((size_t)IN_DIM*HID*2));
  unsigned short* wt2  = (unsigned short*)(ws + alloc((size_t)HID*OUT_DIM*2));
  float* el1   = (float*)(ws + alloc((size_t)N_NODES*HEADS*4));
  float* er1   = (float*)(ws + alloc((size_t)N_NODES*HEADS*4));
  float* el2   = (float*)(ws + alloc((size_t)N_NODES*4));
  float* er2   = (float*)(ws + alloc((size_t)N_NODES*4));
  int* cnt     = (int*)(ws + alloc((size_t)N_NODES*4));
  int* bucket  = (int*)(ws + alloc((size_t)N_NODES*CAP*4));
  int* modep   = (int*)(ws + alloc(256));

  detect_zero_k<<<1+(N_NODES+255)/256,256,0,stream>>>(
      (const unsigned short*)W1, modep, cnt, el2, er2);
  prep2_k<<<WPREP_BLOCKS+(E+255)/256,256,0,stream>>>(
      W1, W2, wt1, wt2, modep, src, dst, cnt, bucket, E);

  // layer 1 (gemm + fused dots1, direct store)
  gemm_k<<<dim3(HID/64,(N_NODES+63)/64),256,0,stream>>>(
      h_in, wt1, f1b, N_NODES, HID, IN_DIM, 1, modep, al1, ar1, el1, er1, 1);
  agg1_k<<<2*N_NODES,64,0,stream>>>(f1b, el1, er1, cnt, bucket, xbuf);

  // layer 2 (gemm + fused dots2, atomic)
  gemm_k<<<dim3(OUT_DIM/64,(N_NODES+63)/64),256,0,stream>>>(
      xbuf, wt2, f2b, N_NODES, OUT_DIM, HID, 0, modep, al2, ar2, el2, er2, 2);
  agg2_k<<<N_NODES,64,0,stream>>>(f2b, el2, er2, cnt, bucket, d_out, modep);
}